// Round 1
// baseline (797.808 us; speedup 1.0000x reference)
//
#include <hip/hip_runtime.h>
#include <math.h>

#define N_NODES 20000
#define N_EDGES 640000

__device__ __forceinline__ float elu_f(float v) { return v > 0.f ? v : expm1f(v); }

// ---------------- CSR build ----------------

__global__ void zero_int_kernel(int* p, int n) {
  int i = blockIdx.x * 256 + threadIdx.x;
  if (i < n) p[i] = 0;
}

__global__ void hist_kernel(const int* __restrict__ dst, int* __restrict__ cnt, int ne) {
  int e = blockIdx.x * 256 + threadIdx.x;
  if (e < ne) atomicAdd(&cnt[dst[e]], 1);
}

__global__ __launch_bounds__(1024) void scan_kernel(const int* __restrict__ cnt,
                                                    int* __restrict__ row_ptr,
                                                    int* __restrict__ row_next, int n) {
  __shared__ int part[1024];
  int t = threadIdx.x;
  int per = (n + 1023) / 1024;
  int base = t * per;
  int local = 0;
  for (int i = 0; i < per; ++i) {
    int idx = base + i;
    if (idx < n) local += cnt[idx];
  }
  part[t] = local;
  __syncthreads();
  for (int off = 1; off < 1024; off <<= 1) {
    int v = (t >= off) ? part[t - off] : 0;
    __syncthreads();
    part[t] += v;
    __syncthreads();
  }
  int prefix = (t == 0) ? 0 : part[t - 1];
  for (int i = 0; i < per; ++i) {
    int idx = base + i;
    if (idx < n) {
      row_ptr[idx] = prefix;
      row_next[idx] = prefix;
      prefix += cnt[idx];
    }
  }
  if (t == 1023) row_ptr[n] = part[1023];
}

__global__ void fill_kernel(const int* __restrict__ src, const int* __restrict__ dst,
                            const float* __restrict__ ea, int* __restrict__ row_next,
                            int* __restrict__ csr_src, int* __restrict__ csr_dst,
                            float* __restrict__ csr_ea, int ne) {
  int e = blockIdx.x * 256 + threadIdx.x;
  if (e >= ne) return;
  int d = dst[e];
  int pos = atomicAdd(&row_next[d], 1);
  csr_src[pos] = src[e];
  csr_dst[pos] = d;
  csr_ea[pos * 3 + 0] = ea[e * 3 + 0];
  csr_ea[pos * 3 + 1] = ea[e * 3 + 1];
  csr_ea[pos * 3 + 2] = ea[e * 3 + 2];
}

// ---------------- input projection ----------------

__global__ void in_proj_kernel(const float* __restrict__ x, const float* __restrict__ Wp,
                               const float* __restrict__ bp, float* __restrict__ h, int n) {
  int i = blockIdx.x * 256 + threadIdx.x;
  if (i >= n * 64) return;
  int node = i >> 6, c = i & 63;
  float v = x[node * 2] * Wp[c] + x[node * 2 + 1] * Wp[64 + c] + bp[c];
  h[i] = elu_f(v);
}

// ---------------- tiled fp32 GEMM: C[M,Nc] = A[M,K] @ B[K,Nc] ----------------

__global__ __launch_bounds__(256) void gemm_kernel(const float* __restrict__ A,
                                                   const float* __restrict__ B,
                                                   float* __restrict__ C,
                                                   int M, int K, int Nc) {
  __shared__ float As[64][33];
  __shared__ float Bs[32][65];
  int t = threadIdx.x;
  int tx = t & 15, ty = t >> 4;
  int row0 = blockIdx.y * 64, col0 = blockIdx.x * 64;
  float acc[4][4] = {};
  for (int k0 = 0; k0 < K; k0 += 32) {
    #pragma unroll
    for (int p = 0; p < 8; ++p) {
      int l = t + p * 256;
      int r = l >> 5, kk = l & 31;
      int gr = row0 + r, gk = k0 + kk;
      float v = 0.f;
      if (gr < M && gk < K) v = A[(size_t)gr * K + gk];
      As[r][kk] = v;
    }
    #pragma unroll
    for (int p = 0; p < 8; ++p) {
      int l = t + p * 256;
      int kr = l >> 6, c = l & 63;
      int gk = k0 + kr, gc = col0 + c;
      float v = 0.f;
      if (gk < K && gc < Nc) v = B[(size_t)gk * Nc + gc];
      Bs[kr][c] = v;
    }
    __syncthreads();
    #pragma unroll
    for (int kk = 0; kk < 32; ++kk) {
      float a[4], b[4];
      #pragma unroll
      for (int i = 0; i < 4; ++i) a[i] = As[ty * 4 + i][kk];
      #pragma unroll
      for (int j = 0; j < 4; ++j) b[j] = Bs[kk][tx * 4 + j];
      #pragma unroll
      for (int i = 0; i < 4; ++i) {
        #pragma unroll
        for (int j = 0; j < 4; ++j) acc[i][j] += a[i] * b[j];
      }
    }
    __syncthreads();
  }
  #pragma unroll
  for (int i = 0; i < 4; ++i) {
    int gr = row0 + ty * 4 + i;
    if (gr >= M) continue;
    #pragma unroll
    for (int j = 0; j < 4; ++j) {
      int gc = col0 + tx * 4 + j;
      if (gc < Nc) C[(size_t)gr * Nc + gc] = acc[i][j];
    }
  }
}

// ---------------- alpha_src / alpha_dst: wave per (n,h), dot over C=64 ----------------

__global__ void alpha_sd_kernel(const float* __restrict__ xh, const float* __restrict__ a_s,
                                const float* __restrict__ a_d, float* __restrict__ alpha_s,
                                float* __restrict__ alpha_d, int n_nodes, int heads) {
  int gid = blockIdx.x * 256 + threadIdx.x;
  int wid = gid >> 6, lane = gid & 63;
  if (wid >= n_nodes * heads) return;
  int h = wid % heads;
  float v = xh[(size_t)wid * 64 + lane];  // wid = n*heads+h, xh row-major [N, heads*64]
  float ps = v * a_s[h * 64 + lane];
  float pd = v * a_d[h * 64 + lane];
  for (int off = 32; off; off >>= 1) {
    ps += __shfl_down(ps, off);
    pd += __shfl_down(pd, off);
  }
  if (lane == 0) {
    alpha_s[wid] = ps;
    alpha_d[wid] = pd;
  }
}

// ---------------- ae_proj[d,h] = sum_c We[d, h*64+c] * ae[h*64+c] ----------------

__global__ void aeproj_kernel(const float* __restrict__ We, const float* __restrict__ ae,
                              float* __restrict__ proj, int heads) {
  int idx = threadIdx.x;
  if (idx >= 3 * heads) return;
  int d = idx / heads, h = idx % heads;
  float s = 0.f;
  for (int c = 0; c < 64; ++c) s += We[d * heads * 64 + h * 64 + c] * ae[h * 64 + c];
  proj[d * heads + h] = s;
}

// ---------------- per-edge alpha (CSR order, pre-activation leaky-relu) ----------------

__global__ void alpha_csr_kernel(const int* __restrict__ csr_src, const int* __restrict__ csr_dst,
                                 const float* __restrict__ csr_ea, const float* __restrict__ as,
                                 const float* __restrict__ ad, const float* __restrict__ proj,
                                 float* __restrict__ alpha, int ne, int heads) {
  int idx = blockIdx.x * 256 + threadIdx.x;
  if (idx >= ne * heads) return;
  int i = idx / heads, h = idx - i * heads;
  int s = csr_src[i], d = csr_dst[i];
  float a = as[s * heads + h] + ad[d * heads + h]
          + csr_ea[i * 3 + 0] * proj[0 * heads + h]
          + csr_ea[i * 3 + 1] * proj[1 * heads + h]
          + csr_ea[i * 3 + 2] * proj[2 * heads + h];
  alpha[idx] = a > 0.f ? a : 0.2f * a;
}

// ---------------- aggregation: one block per dst node ----------------

template <int HC, bool APPLY_ELU>
__global__ void aggregate_kernel(const int* __restrict__ row_ptr, const int* __restrict__ csr_src,
                                 const float* __restrict__ alpha, const float* __restrict__ xh,
                                 const float* __restrict__ bias, float* __restrict__ out) {
  constexpr int H = HC / 64;
  int n = blockIdx.x;
  int t = threadIdx.x;
  int h = t >> 6, lane = t & 63;
  int s0 = row_ptr[n], s1 = row_ptr[n + 1];
  __shared__ float sm[H];
  __shared__ float sinv[H];
  // pass 1: online softmax stats per head (wave h owns head h)
  float m = -INFINITY, ssum = 0.f;
  for (int i = s0 + lane; i < s1; i += 64) {
    float a = alpha[i * H + h];
    float nm = fmaxf(m, a);
    ssum = ssum * __expf(m - nm) + __expf(a - nm);
    m = nm;
  }
  for (int off = 32; off; off >>= 1) {
    float mo = __shfl_down(m, off);
    float so = __shfl_down(ssum, off);
    float nm = fmaxf(m, mo);
    if (nm > -INFINITY) {
      ssum = ssum * __expf(m - nm) + so * __expf(mo - nm);
      m = nm;
    }
  }
  if (lane == 0) {
    sm[h] = m;
    sinv[h] = 1.0f / (ssum + 1e-16f);
  }
  __syncthreads();
  float mh = sm[h], invh = sinv[h];
  // pass 2: weighted accumulate, thread t owns channel t
  float acc = 0.f;
  for (int i = s0; i < s1; ++i) {
    int s = csr_src[i];
    float a = alpha[i * H + h];
    float wgt = __expf(a - mh) * invh;
    acc += xh[(size_t)s * HC + t] * wgt;
  }
  float o = acc + bias[t];
  if (APPLY_ELU) o = elu_f(o);
  out[(size_t)n * HC + t] = o;
}

// ---------------- classifier: wave per node, 64 -> softmax(4) ----------------

__global__ void classifier_kernel(const float* __restrict__ h, const float* __restrict__ Wc,
                                  const float* __restrict__ bc, float* __restrict__ out,
                                  int n_nodes) {
  int gid = blockIdx.x * 256 + threadIdx.x;
  int w = gid >> 6, lane = gid & 63;
  if (w >= n_nodes) return;
  float hv = h[w * 64 + lane];
  float p0 = hv * Wc[lane * 4 + 0];
  float p1 = hv * Wc[lane * 4 + 1];
  float p2 = hv * Wc[lane * 4 + 2];
  float p3 = hv * Wc[lane * 4 + 3];
  for (int off = 32; off; off >>= 1) {
    p0 += __shfl_down(p0, off);
    p1 += __shfl_down(p1, off);
    p2 += __shfl_down(p2, off);
    p3 += __shfl_down(p3, off);
  }
  if (lane == 0) {
    p0 += bc[0]; p1 += bc[1]; p2 += bc[2]; p3 += bc[3];
    float mx = fmaxf(fmaxf(p0, p1), fmaxf(p2, p3));
    float e0 = __expf(p0 - mx), e1 = __expf(p1 - mx), e2 = __expf(p2 - mx), e3 = __expf(p3 - mx);
    float inv = 1.f / (e0 + e1 + e2 + e3);
    out[w * 4 + 0] = e0 * inv;
    out[w * 4 + 1] = e1 * inv;
    out[w * 4 + 2] = e2 * inv;
    out[w * 4 + 3] = e3 * inv;
  }
}

// ---------------- host ----------------

static inline void launch_gemm(const float* A, const float* B, float* C, int M, int K, int Nc,
                               hipStream_t stream) {
  dim3 grid((Nc + 63) / 64, (M + 63) / 64);
  gemm_kernel<<<grid, 256, 0, stream>>>(A, B, C, M, K, Nc);
}

extern "C" void kernel_launch(void* const* d_in, const int* in_sizes, int n_in,
                              void* d_out, int out_size, void* d_ws, size_t ws_size,
                              hipStream_t stream) {
  const float* x   = (const float*)d_in[0];
  const int*   ei  = (const int*)d_in[1];
  const float* ea  = (const float*)d_in[2];
  const float* Wp  = (const float*)d_in[3];
  const float* bp  = (const float*)d_in[4];
  const float* W1  = (const float*)d_in[5];
  const float* We1 = (const float*)d_in[6];
  const float* as1 = (const float*)d_in[7];
  const float* ad1 = (const float*)d_in[8];
  const float* ae1 = (const float*)d_in[9];
  const float* b1  = (const float*)d_in[10];
  const float* W2  = (const float*)d_in[11];
  const float* We2 = (const float*)d_in[12];
  const float* as2 = (const float*)d_in[13];
  const float* ad2 = (const float*)d_in[14];
  const float* ae2 = (const float*)d_in[15];
  const float* b2  = (const float*)d_in[16];
  const float* W3  = (const float*)d_in[17];
  const float* We3 = (const float*)d_in[18];
  const float* as3 = (const float*)d_in[19];
  const float* ad3 = (const float*)d_in[20];
  const float* ae3 = (const float*)d_in[21];
  const float* b3  = (const float*)d_in[22];
  const float* Wc  = (const float*)d_in[23];
  const float* bc  = (const float*)d_in[24];
  float* out = (float*)d_out;

  const int* src = ei;
  const int* dst = ei + N_EDGES;

  char* wptr = (char*)d_ws;
  auto alloc = [&](size_t bytes) {
    char* p = wptr;
    wptr += (bytes + 255) & ~(size_t)255;
    return p;
  };
  int*   cnt      = (int*)alloc((size_t)N_NODES * 4);
  int*   row_ptr  = (int*)alloc((size_t)(N_NODES + 1) * 4);
  int*   row_next = (int*)alloc((size_t)N_NODES * 4);
  int*   csr_src  = (int*)alloc((size_t)N_EDGES * 4);
  int*   csr_dst  = (int*)alloc((size_t)N_EDGES * 4);
  float* csr_ea   = (float*)alloc((size_t)N_EDGES * 3 * 4);
  float* hA       = (float*)alloc((size_t)N_NODES * 256 * 4);
  float* hB       = (float*)alloc((size_t)N_NODES * 256 * 4);
  float* alp_s    = (float*)alloc((size_t)N_NODES * 4 * 4);
  float* alp_d    = (float*)alloc((size_t)N_NODES * 4 * 4);
  float* alp_e    = (float*)alloc((size_t)N_EDGES * 4 * 4);
  float* proj     = (float*)alloc(64);

  // ---- CSR build (per launch; deterministic structure, order-free math) ----
  zero_int_kernel<<<(N_NODES + 255) / 256, 256, 0, stream>>>(cnt, N_NODES);
  hist_kernel<<<(N_EDGES + 255) / 256, 256, 0, stream>>>(dst, cnt, N_EDGES);
  scan_kernel<<<1, 1024, 0, stream>>>(cnt, row_ptr, row_next, N_NODES);
  fill_kernel<<<(N_EDGES + 255) / 256, 256, 0, stream>>>(src, dst, ea, row_next,
                                                         csr_src, csr_dst, csr_ea, N_EDGES);

  // ---- input projection ----
  in_proj_kernel<<<N_NODES * 64 / 256, 256, 0, stream>>>(x, Wp, bp, hA, N_NODES);

  // ---- layer 1: 64 -> 4 heads x 64, ELU ----
  launch_gemm(hA, W1, hB, N_NODES, 64, 256, stream);
  alpha_sd_kernel<<<N_NODES * 4 * 64 / 256, 256, 0, stream>>>(hB, as1, ad1, alp_s, alp_d, N_NODES, 4);
  aeproj_kernel<<<1, 64, 0, stream>>>(We1, ae1, proj, 4);
  alpha_csr_kernel<<<(N_EDGES * 4 + 255) / 256, 256, 0, stream>>>(csr_src, csr_dst, csr_ea,
                                                                  alp_s, alp_d, proj, alp_e,
                                                                  N_EDGES, 4);
  aggregate_kernel<256, true><<<N_NODES, 256, 0, stream>>>(row_ptr, csr_src, alp_e, hB, b1, hA);

  // ---- layer 2: 256 -> 4 heads x 64, ELU ----
  launch_gemm(hA, W2, hB, N_NODES, 256, 256, stream);
  alpha_sd_kernel<<<N_NODES * 4 * 64 / 256, 256, 0, stream>>>(hB, as2, ad2, alp_s, alp_d, N_NODES, 4);
  aeproj_kernel<<<1, 64, 0, stream>>>(We2, ae2, proj, 4);
  alpha_csr_kernel<<<(N_EDGES * 4 + 255) / 256, 256, 0, stream>>>(csr_src, csr_dst, csr_ea,
                                                                  alp_s, alp_d, proj, alp_e,
                                                                  N_EDGES, 4);
  aggregate_kernel<256, true><<<N_NODES, 256, 0, stream>>>(row_ptr, csr_src, alp_e, hB, b2, hA);

  // ---- layer 3: 256 -> 1 head x 64, no ELU ----
  launch_gemm(hA, W3, hB, N_NODES, 256, 64, stream);
  alpha_sd_kernel<<<N_NODES * 1 * 64 / 256, 256, 0, stream>>>(hB, as3, ad3, alp_s, alp_d, N_NODES, 1);
  aeproj_kernel<<<1, 64, 0, stream>>>(We3, ae3, proj, 1);
  alpha_csr_kernel<<<(N_EDGES * 1 + 255) / 256, 256, 0, stream>>>(csr_src, csr_dst, csr_ea,
                                                                  alp_s, alp_d, proj, alp_e,
                                                                  N_EDGES, 1);
  aggregate_kernel<64, false><<<N_NODES, 64, 0, stream>>>(row_ptr, csr_src, alp_e, hB, b3, hA);

  // ---- classifier + softmax ----
  classifier_kernel<<<N_NODES * 64 / 256, 256, 0, stream>>>(hA, Wc, bc, out, N_NODES);
}

// Round 2
// 732.468 us; speedup vs baseline: 1.0892x; 1.0892x over previous
//
#include <hip/hip_runtime.h>
#include <math.h>

#define N_NODES 20000
#define N_EDGES 640000

__device__ __forceinline__ float elu_f(float v) { return v > 0.f ? v : expm1f(v); }

// ---------------- CSR build ----------------

__global__ void zero_int_kernel(int* p, int n) {
  int i = blockIdx.x * 256 + threadIdx.x;
  if (i < n) p[i] = 0;
}

__global__ void hist_kernel(const int* __restrict__ dst, int* __restrict__ cnt, int ne) {
  int e = blockIdx.x * 256 + threadIdx.x;
  if (e < ne) atomicAdd(&cnt[dst[e]], 1);
}

__global__ __launch_bounds__(1024) void scan_kernel(const int* __restrict__ cnt,
                                                    int* __restrict__ row_ptr,
                                                    int* __restrict__ row_next, int n) {
  __shared__ int part[1024];
  int t = threadIdx.x;
  int per = (n + 1023) / 1024;
  int base = t * per;
  int local = 0;
  for (int i = 0; i < per; ++i) {
    int idx = base + i;
    if (idx < n) local += cnt[idx];
  }
  part[t] = local;
  __syncthreads();
  for (int off = 1; off < 1024; off <<= 1) {
    int v = (t >= off) ? part[t - off] : 0;
    __syncthreads();
    part[t] += v;
    __syncthreads();
  }
  int prefix = (t == 0) ? 0 : part[t - 1];
  for (int i = 0; i < per; ++i) {
    int idx = base + i;
    if (idx < n) {
      row_ptr[idx] = prefix;
      row_next[idx] = prefix;
      prefix += cnt[idx];
    }
  }
  if (t == 1023) row_ptr[n] = part[1023];
}

__global__ void fill_kernel(const int* __restrict__ src, const int* __restrict__ dst,
                            const float* __restrict__ ea, int* __restrict__ row_next,
                            int* __restrict__ csr_src, int* __restrict__ csr_dst,
                            float* __restrict__ csr_ea, int ne) {
  int e = blockIdx.x * 256 + threadIdx.x;
  if (e >= ne) return;
  int d = dst[e];
  int pos = atomicAdd(&row_next[d], 1);
  csr_src[pos] = src[e];
  csr_dst[pos] = d;
  csr_ea[pos * 3 + 0] = ea[e * 3 + 0];
  csr_ea[pos * 3 + 1] = ea[e * 3 + 1];
  csr_ea[pos * 3 + 2] = ea[e * 3 + 2];
}

// ---------------- input projection ----------------

__global__ void in_proj_kernel(const float* __restrict__ x, const float* __restrict__ Wp,
                               const float* __restrict__ bp, float* __restrict__ h, int n) {
  int i = blockIdx.x * 256 + threadIdx.x;
  if (i >= n * 64) return;
  int node = i >> 6, c = i & 63;
  float v = x[node * 2] * Wp[c] + x[node * 2 + 1] * Wp[64 + c] + bp[c];
  h[i] = elu_f(v);
}

// ---------------- tiled fp32 GEMM: C[M,Nc] = A[M,K] @ B[K,Nc] ----------------

__global__ __launch_bounds__(256) void gemm_kernel(const float* __restrict__ A,
                                                   const float* __restrict__ B,
                                                   float* __restrict__ C,
                                                   int M, int K, int Nc) {
  __shared__ float As[64][33];
  __shared__ float Bs[32][65];
  int t = threadIdx.x;
  int tx = t & 15, ty = t >> 4;
  int row0 = blockIdx.y * 64, col0 = blockIdx.x * 64;
  float acc[4][4] = {};
  for (int k0 = 0; k0 < K; k0 += 32) {
    #pragma unroll
    for (int p = 0; p < 8; ++p) {
      int l = t + p * 256;
      int r = l >> 5, kk = l & 31;
      int gr = row0 + r, gk = k0 + kk;
      float v = 0.f;
      if (gr < M && gk < K) v = A[(size_t)gr * K + gk];
      As[r][kk] = v;
    }
    #pragma unroll
    for (int p = 0; p < 8; ++p) {
      int l = t + p * 256;
      int kr = l >> 6, c = l & 63;
      int gk = k0 + kr, gc = col0 + c;
      float v = 0.f;
      if (gk < K && gc < Nc) v = B[(size_t)gk * Nc + gc];
      Bs[kr][c] = v;
    }
    __syncthreads();
    #pragma unroll
    for (int kk = 0; kk < 32; ++kk) {
      float a[4], b[4];
      #pragma unroll
      for (int i = 0; i < 4; ++i) a[i] = As[ty * 4 + i][kk];
      #pragma unroll
      for (int j = 0; j < 4; ++j) b[j] = Bs[kk][tx * 4 + j];
      #pragma unroll
      for (int i = 0; i < 4; ++i) {
        #pragma unroll
        for (int j = 0; j < 4; ++j) acc[i][j] += a[i] * b[j];
      }
    }
    __syncthreads();
  }
  #pragma unroll
  for (int i = 0; i < 4; ++i) {
    int gr = row0 + ty * 4 + i;
    if (gr >= M) continue;
    #pragma unroll
    for (int j = 0; j < 4; ++j) {
      int gc = col0 + tx * 4 + j;
      if (gc < Nc) C[(size_t)gr * Nc + gc] = acc[i][j];
    }
  }
}

// ---------------- alpha_src / alpha_dst: wave per (n,h), dot over C=64 ----------------

__global__ void alpha_sd_kernel(const float* __restrict__ xh, const float* __restrict__ a_s,
                                const float* __restrict__ a_d, float* __restrict__ alpha_s,
                                float* __restrict__ alpha_d, int n_nodes, int heads) {
  int gid = blockIdx.x * 256 + threadIdx.x;
  int wid = gid >> 6, lane = gid & 63;
  if (wid >= n_nodes * heads) return;
  int h = wid % heads;
  float v = xh[(size_t)wid * 64 + lane];
  float ps = v * a_s[h * 64 + lane];
  float pd = v * a_d[h * 64 + lane];
  for (int off = 32; off; off >>= 1) {
    ps += __shfl_down(ps, off);
    pd += __shfl_down(pd, off);
  }
  if (lane == 0) {
    alpha_s[wid] = ps;
    alpha_d[wid] = pd;
  }
}

// ---------------- ae_proj[d,h] = sum_c We[d, h*64+c] * ae[h*64+c] ----------------

__global__ void aeproj_kernel(const float* __restrict__ We, const float* __restrict__ ae,
                              float* __restrict__ proj, int heads) {
  int idx = threadIdx.x;
  if (idx >= 3 * heads) return;
  int d = idx / heads, h = idx % heads;
  float s = 0.f;
  for (int c = 0; c < 64; ++c) s += We[d * heads * 64 + h * 64 + c] * ae[h * 64 + c];
  proj[d * heads + h] = s;
}

// ---------------- per-edge alpha (CSR order, leaky-relu) ----------------

__global__ void alpha_csr_kernel(const int* __restrict__ csr_src, const int* __restrict__ csr_dst,
                                 const float* __restrict__ csr_ea, const float* __restrict__ as,
                                 const float* __restrict__ ad, const float* __restrict__ proj,
                                 float* __restrict__ alpha, int ne, int heads) {
  int idx = blockIdx.x * 256 + threadIdx.x;
  if (idx >= ne * heads) return;
  int i = idx / heads, h = idx - i * heads;
  int s = csr_src[i], d = csr_dst[i];
  float a = as[s * heads + h] + ad[d * heads + h]
          + csr_ea[i * 3 + 0] * proj[0 * heads + h]
          + csr_ea[i * 3 + 1] * proj[1 * heads + h]
          + csr_ea[i * 3 + 2] * proj[2 * heads + h];
  alpha[idx] = a > 0.f ? a : 0.2f * a;
}

// ---------------- softmax stats per (node, head): m and 1/(sum+eps) ----------------

template <int H>
__global__ void softmax_stats_kernel(const int* __restrict__ row_ptr,
                                     const float* __restrict__ alpha,
                                     float2* __restrict__ stats, int n_nodes) {
  int gid = blockIdx.x * 256 + threadIdx.x;
  int wid = gid >> 6, lane = gid & 63;
  if (wid >= n_nodes * H) return;
  int n = wid / H, h = wid % H;
  int s0 = row_ptr[n], s1 = row_ptr[n + 1];
  float m = -INFINITY, ssum = 0.f;
  for (int i = s0 + lane; i < s1; i += 64) {
    float a = alpha[i * H + h];
    float nm = fmaxf(m, a);
    ssum = ssum * __expf(m - nm) + __expf(a - nm);
    m = nm;
  }
  for (int off = 32; off; off >>= 1) {
    float mo = __shfl_down(m, off);
    float so = __shfl_down(ssum, off);
    float nm = fmaxf(m, mo);
    if (nm > -INFINITY) {
      ssum = ssum * __expf(m - nm) + so * __expf(mo - nm);
      m = nm;
    }
  }
  if (lane == 0) stats[wid] = make_float2(m, 1.0f / (ssum + 1e-16f));
}

// ---------------- normalize: attn = exp(alpha - m)*inv, in-place ----------------

template <int H>
__global__ void attn_norm_kernel(const int* __restrict__ csr_dst,
                                 const float2* __restrict__ stats,
                                 float* __restrict__ alpha, int ne) {
  int idx = blockIdx.x * 256 + threadIdx.x;
  if (idx >= ne * H) return;
  int i = idx / H, h = idx - i * H;
  int d = csr_dst[i];
  float2 st = stats[d * H + h];
  alpha[idx] = __expf(alpha[idx] - st.x) * st.y;
}

// ---------------- aggregation: one block per dst node, float4 + multi-edge slots ----------------
// thread t: edge slot = t / L, lane l = t % L, channels [4l, 4l+4), L = HC/4 lanes per slot.

template <int HC, bool APPLY_ELU>
__global__ __launch_bounds__(256) void aggregate_kernel(const int* __restrict__ row_ptr,
                                                        const int* __restrict__ csr_src,
                                                        const float* __restrict__ attn,
                                                        const float* __restrict__ xh,
                                                        const float* __restrict__ bias,
                                                        float* __restrict__ out) {
  constexpr int H = HC / 64;   // heads
  constexpr int L = HC / 4;    // lanes per edge slot
  constexpr int S = 256 / L;   // edge slots in flight
  int n = blockIdx.x;
  int t = threadIdx.x;
  int slot = t / L;
  int l = t % L;
  int head = (4 * l) >> 6;     // head owning channels 4l..4l+3
  int s0 = row_ptr[n], s1 = row_ptr[n + 1];
  const float4* __restrict__ xh4 = (const float4*)xh;
  float4 acc = make_float4(0.f, 0.f, 0.f, 0.f);
  for (int i = s0 + slot; i < s1; i += S) {
    int s = csr_src[i];
    float w = attn[i * H + head];
    float4 v = xh4[(size_t)s * L + l];
    acc.x += v.x * w;
    acc.y += v.y * w;
    acc.z += v.z * w;
    acc.w += v.w * w;
  }
  __shared__ float4 red[256];
  red[t] = acc;
  __syncthreads();
  if (t < L) {
    float4 a = red[t];
    #pragma unroll
    for (int s = 1; s < S; ++s) {
      float4 b = red[t + s * L];
      a.x += b.x; a.y += b.y; a.z += b.z; a.w += b.w;
    }
    float4 bv = ((const float4*)bias)[l];
    a.x += bv.x; a.y += bv.y; a.z += bv.z; a.w += bv.w;
    if (APPLY_ELU) {
      a.x = elu_f(a.x); a.y = elu_f(a.y); a.z = elu_f(a.z); a.w = elu_f(a.w);
    }
    ((float4*)out)[(size_t)n * L + l] = a;
  }
}

// ---------------- classifier: wave per node, 64 -> softmax(4) ----------------

__global__ void classifier_kernel(const float* __restrict__ h, const float* __restrict__ Wc,
                                  const float* __restrict__ bc, float* __restrict__ out,
                                  int n_nodes) {
  int gid = blockIdx.x * 256 + threadIdx.x;
  int w = gid >> 6, lane = gid & 63;
  if (w >= n_nodes) return;
  float hv = h[w * 64 + lane];
  float p0 = hv * Wc[lane * 4 + 0];
  float p1 = hv * Wc[lane * 4 + 1];
  float p2 = hv * Wc[lane * 4 + 2];
  float p3 = hv * Wc[lane * 4 + 3];
  for (int off = 32; off; off >>= 1) {
    p0 += __shfl_down(p0, off);
    p1 += __shfl_down(p1, off);
    p2 += __shfl_down(p2, off);
    p3 += __shfl_down(p3, off);
  }
  if (lane == 0) {
    p0 += bc[0]; p1 += bc[1]; p2 += bc[2]; p3 += bc[3];
    float mx = fmaxf(fmaxf(p0, p1), fmaxf(p2, p3));
    float e0 = __expf(p0 - mx), e1 = __expf(p1 - mx), e2 = __expf(p2 - mx), e3 = __expf(p3 - mx);
    float inv = 1.f / (e0 + e1 + e2 + e3);
    out[w * 4 + 0] = e0 * inv;
    out[w * 4 + 1] = e1 * inv;
    out[w * 4 + 2] = e2 * inv;
    out[w * 4 + 3] = e3 * inv;
  }
}

// ---------------- host ----------------

static inline void launch_gemm(const float* A, const float* B, float* C, int M, int K, int Nc,
                               hipStream_t stream) {
  dim3 grid((Nc + 63) / 64, (M + 63) / 64);
  gemm_kernel<<<grid, 256, 0, stream>>>(A, B, C, M, K, Nc);
}

extern "C" void kernel_launch(void* const* d_in, const int* in_sizes, int n_in,
                              void* d_out, int out_size, void* d_ws, size_t ws_size,
                              hipStream_t stream) {
  const float* x   = (const float*)d_in[0];
  const int*   ei  = (const int*)d_in[1];
  const float* ea  = (const float*)d_in[2];
  const float* Wp  = (const float*)d_in[3];
  const float* bp  = (const float*)d_in[4];
  const float* W1  = (const float*)d_in[5];
  const float* We1 = (const float*)d_in[6];
  const float* as1 = (const float*)d_in[7];
  const float* ad1 = (const float*)d_in[8];
  const float* ae1 = (const float*)d_in[9];
  const float* b1  = (const float*)d_in[10];
  const float* W2  = (const float*)d_in[11];
  const float* We2 = (const float*)d_in[12];
  const float* as2 = (const float*)d_in[13];
  const float* ad2 = (const float*)d_in[14];
  const float* ae2 = (const float*)d_in[15];
  const float* b2  = (const float*)d_in[16];
  const float* W3  = (const float*)d_in[17];
  const float* We3 = (const float*)d_in[18];
  const float* as3 = (const float*)d_in[19];
  const float* ad3 = (const float*)d_in[20];
  const float* ae3 = (const float*)d_in[21];
  const float* b3  = (const float*)d_in[22];
  const float* Wc  = (const float*)d_in[23];
  const float* bc  = (const float*)d_in[24];
  float* out = (float*)d_out;

  const int* src = ei;
  const int* dst = ei + N_EDGES;

  char* wptr = (char*)d_ws;
  auto alloc = [&](size_t bytes) {
    char* p = wptr;
    wptr += (bytes + 255) & ~(size_t)255;
    return p;
  };
  int*    cnt      = (int*)alloc((size_t)N_NODES * 4);
  int*    row_ptr  = (int*)alloc((size_t)(N_NODES + 1) * 4);
  int*    row_next = (int*)alloc((size_t)N_NODES * 4);
  int*    csr_src  = (int*)alloc((size_t)N_EDGES * 4);
  int*    csr_dst  = (int*)alloc((size_t)N_EDGES * 4);
  float*  csr_ea   = (float*)alloc((size_t)N_EDGES * 3 * 4);
  float*  hA       = (float*)alloc((size_t)N_NODES * 256 * 4);
  float*  hB       = (float*)alloc((size_t)N_NODES * 256 * 4);
  float*  alp_s    = (float*)alloc((size_t)N_NODES * 4 * 4);
  float*  alp_d    = (float*)alloc((size_t)N_NODES * 4 * 4);
  float*  alp_e    = (float*)alloc((size_t)N_EDGES * 4 * 4);
  float2* stats    = (float2*)alloc((size_t)N_NODES * 4 * 8);
  float*  proj     = (float*)alloc(64);

  // ---- CSR build ----
  zero_int_kernel<<<(N_NODES + 255) / 256, 256, 0, stream>>>(cnt, N_NODES);
  hist_kernel<<<(N_EDGES + 255) / 256, 256, 0, stream>>>(dst, cnt, N_EDGES);
  scan_kernel<<<1, 1024, 0, stream>>>(cnt, row_ptr, row_next, N_NODES);
  fill_kernel<<<(N_EDGES + 255) / 256, 256, 0, stream>>>(src, dst, ea, row_next,
                                                         csr_src, csr_dst, csr_ea, N_EDGES);

  // ---- input projection ----
  in_proj_kernel<<<N_NODES * 64 / 256, 256, 0, stream>>>(x, Wp, bp, hA, N_NODES);

  // ---- layer 1: 64 -> 4 heads x 64, ELU ----
  launch_gemm(hA, W1, hB, N_NODES, 64, 256, stream);
  alpha_sd_kernel<<<N_NODES * 4 * 64 / 256, 256, 0, stream>>>(hB, as1, ad1, alp_s, alp_d, N_NODES, 4);
  aeproj_kernel<<<1, 64, 0, stream>>>(We1, ae1, proj, 4);
  alpha_csr_kernel<<<(N_EDGES * 4 + 255) / 256, 256, 0, stream>>>(csr_src, csr_dst, csr_ea,
                                                                  alp_s, alp_d, proj, alp_e,
                                                                  N_EDGES, 4);
  softmax_stats_kernel<4><<<(N_NODES * 4 * 64 + 255) / 256, 256, 0, stream>>>(row_ptr, alp_e, stats, N_NODES);
  attn_norm_kernel<4><<<(N_EDGES * 4 + 255) / 256, 256, 0, stream>>>(csr_dst, stats, alp_e, N_EDGES);
  aggregate_kernel<256, true><<<N_NODES, 256, 0, stream>>>(row_ptr, csr_src, alp_e, hB, b1, hA);

  // ---- layer 2: 256 -> 4 heads x 64, ELU ----
  launch_gemm(hA, W2, hB, N_NODES, 256, 256, stream);
  alpha_sd_kernel<<<N_NODES * 4 * 64 / 256, 256, 0, stream>>>(hB, as2, ad2, alp_s, alp_d, N_NODES, 4);
  aeproj_kernel<<<1, 64, 0, stream>>>(We2, ae2, proj, 4);
  alpha_csr_kernel<<<(N_EDGES * 4 + 255) / 256, 256, 0, stream>>>(csr_src, csr_dst, csr_ea,
                                                                  alp_s, alp_d, proj, alp_e,
                                                                  N_EDGES, 4);
  softmax_stats_kernel<4><<<(N_NODES * 4 * 64 + 255) / 256, 256, 0, stream>>>(row_ptr, alp_e, stats, N_NODES);
  attn_norm_kernel<4><<<(N_EDGES * 4 + 255) / 256, 256, 0, stream>>>(csr_dst, stats, alp_e, N_EDGES);
  aggregate_kernel<256, true><<<N_NODES, 256, 0, stream>>>(row_ptr, csr_src, alp_e, hB, b2, hA);

  // ---- layer 3: 256 -> 1 head x 64, no ELU ----
  launch_gemm(hA, W3, hB, N_NODES, 256, 64, stream);
  alpha_sd_kernel<<<N_NODES * 1 * 64 / 256, 256, 0, stream>>>(hB, as3, ad3, alp_s, alp_d, N_NODES, 1);
  aeproj_kernel<<<1, 64, 0, stream>>>(We3, ae3, proj, 1);
  alpha_csr_kernel<<<(N_EDGES * 1 + 255) / 256, 256, 0, stream>>>(csr_src, csr_dst, csr_ea,
                                                                  alp_s, alp_d, proj, alp_e,
                                                                  N_EDGES, 1);
  softmax_stats_kernel<1><<<(N_NODES * 1 * 64 + 255) / 256, 256, 0, stream>>>(row_ptr, alp_e, stats, N_NODES);
  attn_norm_kernel<1><<<(N_EDGES * 1 + 255) / 256, 256, 0, stream>>>(csr_dst, stats, alp_e, N_EDGES);
  aggregate_kernel<64, false><<<N_NODES, 256, 0, stream>>>(row_ptr, csr_src, alp_e, hB, b3, hA);

  // ---- classifier + softmax ----
  classifier_kernel<<<N_NODES * 64 / 256, 256, 0, stream>>>(hA, Wc, bc, out, N_NODES);
}

// Round 3
// 573.636 us; speedup vs baseline: 1.3908x; 1.2769x over previous
//
#include <hip/hip_runtime.h>
#include <math.h>

#define N_NODES 20000
#define N_EDGES 640000

typedef __attribute__((ext_vector_type(8))) short short8;
typedef __attribute__((ext_vector_type(4))) float floatx4;

__device__ __forceinline__ float elu_f(float v) { return v > 0.f ? v : expm1f(v); }

__device__ __forceinline__ unsigned short bf16_rne(float f) {
  union { float f; unsigned u; } v;
  v.f = f;
  unsigned r = v.u + 0x7FFF + ((v.u >> 16) & 1);
  return (unsigned short)(r >> 16);
}

// ---------------- CSR build ----------------

__global__ void zero_int_kernel(int* p, int n) {
  int i = blockIdx.x * 256 + threadIdx.x;
  if (i < n) p[i] = 0;
}

__global__ void hist_kernel(const int* __restrict__ dst, int* __restrict__ cnt, int ne) {
  int e = blockIdx.x * 256 + threadIdx.x;
  if (e < ne) atomicAdd(&cnt[dst[e]], 1);
}

__global__ __launch_bounds__(1024) void scan_kernel(const int* __restrict__ cnt,
                                                    int* __restrict__ row_ptr,
                                                    int* __restrict__ row_next, int n) {
  __shared__ int part[1024];
  int t = threadIdx.x;
  int per = (n + 1023) / 1024;
  int base = t * per;
  int local = 0;
  for (int i = 0; i < per; ++i) {
    int idx = base + i;
    if (idx < n) local += cnt[idx];
  }
  part[t] = local;
  __syncthreads();
  for (int off = 1; off < 1024; off <<= 1) {
    int v = (t >= off) ? part[t - off] : 0;
    __syncthreads();
    part[t] += v;
    __syncthreads();
  }
  int prefix = (t == 0) ? 0 : part[t - 1];
  for (int i = 0; i < per; ++i) {
    int idx = base + i;
    if (idx < n) {
      row_ptr[idx] = prefix;
      row_next[idx] = prefix;
      prefix += cnt[idx];
    }
  }
  if (t == 1023) row_ptr[n] = part[1023];
}

__global__ void fill_kernel(const int* __restrict__ src, const int* __restrict__ dst,
                            const float* __restrict__ ea, int* __restrict__ row_next,
                            int* __restrict__ csr_src, int* __restrict__ csr_dst,
                            float* __restrict__ csr_ea, int ne) {
  int e = blockIdx.x * 256 + threadIdx.x;
  if (e >= ne) return;
  int d = dst[e];
  int pos = atomicAdd(&row_next[d], 1);
  csr_src[pos] = src[e];
  csr_dst[pos] = d;
  csr_ea[pos * 3 + 0] = ea[e * 3 + 0];
  csr_ea[pos * 3 + 1] = ea[e * 3 + 1];
  csr_ea[pos * 3 + 2] = ea[e * 3 + 2];
}

// ---------------- weight cast+transpose: Bt[n][k] = bf16(W[k][n]) ----------------

__global__ void wt_bf_kernel(const float* __restrict__ W, unsigned short* __restrict__ Bt,
                             int K, int Nc) {
  int idx = blockIdx.x * 256 + threadIdx.x;
  if (idx >= K * Nc) return;
  int k = idx / Nc, n = idx - k * Nc;  // coalesced read of W
  Bt[(size_t)n * K + k] = bf16_rne(W[idx]);
}

// ---------------- input projection (emit bf16 for GEMM1) ----------------

__global__ void in_proj_kernel(const float* __restrict__ x, const float* __restrict__ Wp,
                               const float* __restrict__ bp, unsigned short* __restrict__ h_bf,
                               int n) {
  int i = blockIdx.x * 256 + threadIdx.x;
  if (i >= n * 64) return;
  int node = i >> 6, c = i & 63;
  float v = x[node * 2] * Wp[c] + x[node * 2 + 1] * Wp[64 + c] + bp[c];
  h_bf[i] = bf16_rne(elu_f(v));
}

// ---------------- MFMA bf16 GEMM: C[M,Nc] = A[M,K] @ B[K,Nc], B given as Bt[Nc][K] ----
// block = 256 threads = 4 waves; tile 64 rows x 64 cols; K-step 32.
// wave w owns rows [w*16, w*16+16); 4 MFMA sub-tiles of 16 cols each.

template <int KDIM>
__global__ __launch_bounds__(256) void mfma_gemm_kernel(const unsigned short* __restrict__ A,
                                                        const unsigned short* __restrict__ Bt,
                                                        float* __restrict__ C,
                                                        int M, int Nc) {
  __shared__ unsigned short As[64][40];  // row stride 80 B (16B-aligned, odd word stride)
  __shared__ unsigned short Bs[64][40];  // Bs[n][k]
  int t = threadIdx.x;
  int wave = t >> 6, lane = t & 63;
  int m_frag = lane & 15, quad = lane >> 4;
  int row0 = blockIdx.y * 64, col0 = blockIdx.x * 64;
  int lr = t >> 2;           // 0..63: staging row (A) / col (B)
  int lk = (t & 3) * 8;      // staging k offset (8 bf16 = 16 B per thread)
  floatx4 acc[4];
  #pragma unroll
  for (int c = 0; c < 4; ++c) acc[c] = (floatx4){0.f, 0.f, 0.f, 0.f};

  for (int k0 = 0; k0 < KDIM; k0 += 32) {
    int gr = row0 + lr;
    short8 av = {0, 0, 0, 0, 0, 0, 0, 0};
    if (gr < M) av = *(const short8*)(A + (size_t)gr * KDIM + k0 + lk);
    *(short8*)(&As[lr][lk]) = av;
    short8 bv = *(const short8*)(Bt + (size_t)(col0 + lr) * KDIM + k0 + lk);
    *(short8*)(&Bs[lr][lk]) = bv;
    __syncthreads();
    short8 a = *(const short8*)(&As[wave * 16 + m_frag][quad * 8]);
    #pragma unroll
    for (int c = 0; c < 4; ++c) {
      short8 b = *(const short8*)(&Bs[c * 16 + m_frag][quad * 8]);
      acc[c] = __builtin_amdgcn_mfma_f32_16x16x32_bf16(a, b, acc[c], 0, 0, 0);
    }
    __syncthreads();
  }
  #pragma unroll
  for (int c = 0; c < 4; ++c) {
    #pragma unroll
    for (int i = 0; i < 4; ++i) {
      int gr = row0 + wave * 16 + quad * 4 + i;
      if (gr < M) C[(size_t)gr * Nc + col0 + c * 16 + m_frag] = acc[c][i];
    }
  }
}

// ---------------- alpha_src / alpha_dst: wave per (n,h), dot over C=64 ----------------

__global__ void alpha_sd_kernel(const float* __restrict__ xh, const float* __restrict__ a_s,
                                const float* __restrict__ a_d, float* __restrict__ alpha_s,
                                float* __restrict__ alpha_d, int n_nodes, int heads) {
  int gid = blockIdx.x * 256 + threadIdx.x;
  int wid = gid >> 6, lane = gid & 63;
  if (wid >= n_nodes * heads) return;
  int h = wid % heads;
  float v = xh[(size_t)wid * 64 + lane];
  float ps = v * a_s[h * 64 + lane];
  float pd = v * a_d[h * 64 + lane];
  for (int off = 32; off; off >>= 1) {
    ps += __shfl_down(ps, off);
    pd += __shfl_down(pd, off);
  }
  if (lane == 0) {
    alpha_s[wid] = ps;
    alpha_d[wid] = pd;
  }
}

// ---------------- ae_proj[d,h] = sum_c We[d, h*64+c] * ae[h*64+c] ----------------

__global__ void aeproj_kernel(const float* __restrict__ We, const float* __restrict__ ae,
                              float* __restrict__ proj, int heads) {
  int idx = threadIdx.x;
  if (idx >= 3 * heads) return;
  int d = idx / heads, h = idx % heads;
  float s = 0.f;
  for (int c = 0; c < 64; ++c) s += We[d * heads * 64 + h * 64 + c] * ae[h * 64 + c];
  proj[d * heads + h] = s;
}

// ---------------- per-edge alpha (CSR order, leaky-relu) ----------------

__global__ void alpha_csr_kernel(const int* __restrict__ csr_src, const int* __restrict__ csr_dst,
                                 const float* __restrict__ csr_ea, const float* __restrict__ as,
                                 const float* __restrict__ ad, const float* __restrict__ proj,
                                 float* __restrict__ alpha, int ne, int heads) {
  int idx = blockIdx.x * 256 + threadIdx.x;
  if (idx >= ne * heads) return;
  int i = idx / heads, h = idx - i * heads;
  int s = csr_src[i], d = csr_dst[i];
  float a = as[s * heads + h] + ad[d * heads + h]
          + csr_ea[i * 3 + 0] * proj[0 * heads + h]
          + csr_ea[i * 3 + 1] * proj[1 * heads + h]
          + csr_ea[i * 3 + 2] * proj[2 * heads + h];
  alpha[idx] = a > 0.f ? a : 0.2f * a;
}

// ---------------- softmax stats per (node, head): m and 1/(sum+eps) ----------------

template <int H>
__global__ void softmax_stats_kernel(const int* __restrict__ row_ptr,
                                     const float* __restrict__ alpha,
                                     float2* __restrict__ stats, int n_nodes) {
  int gid = blockIdx.x * 256 + threadIdx.x;
  int wid = gid >> 6, lane = gid & 63;
  if (wid >= n_nodes * H) return;
  int n = wid / H, h = wid % H;
  int s0 = row_ptr[n], s1 = row_ptr[n + 1];
  float m = -INFINITY, ssum = 0.f;
  for (int i = s0 + lane; i < s1; i += 64) {
    float a = alpha[i * H + h];
    float nm = fmaxf(m, a);
    ssum = ssum * __expf(m - nm) + __expf(a - nm);
    m = nm;
  }
  for (int off = 32; off; off >>= 1) {
    float mo = __shfl_down(m, off);
    float so = __shfl_down(ssum, off);
    float nm = fmaxf(m, mo);
    if (nm > -INFINITY) {
      ssum = ssum * __expf(m - nm) + so * __expf(mo - nm);
      m = nm;
    }
  }
  if (lane == 0) stats[wid] = make_float2(m, 1.0f / (ssum + 1e-16f));
}

// ---------------- normalize: attn = exp(alpha - m)*inv, in-place ----------------

template <int H>
__global__ void attn_norm_kernel(const int* __restrict__ csr_dst,
                                 const float2* __restrict__ stats,
                                 float* __restrict__ alpha, int ne) {
  int idx = blockIdx.x * 256 + threadIdx.x;
  if (idx >= ne * H) return;
  int i = idx / H, h = idx - i * H;
  int d = csr_dst[i];
  float2 st = stats[d * H + h];
  alpha[idx] = __expf(alpha[idx] - st.x) * st.y;
}

// ---------------- aggregation: one block per dst node, float4 + multi-edge slots ----------------

template <int HC, bool APPLY_ELU, bool OUT_BF>
__global__ __launch_bounds__(256) void aggregate_kernel(const int* __restrict__ row_ptr,
                                                        const int* __restrict__ csr_src,
                                                        const float* __restrict__ attn,
                                                        const float* __restrict__ xh,
                                                        const float* __restrict__ bias,
                                                        float* __restrict__ out,
                                                        unsigned short* __restrict__ out_bf) {
  constexpr int H = HC / 64;   // heads
  constexpr int L = HC / 4;    // lanes per edge slot
  constexpr int S = 256 / L;   // edge slots in flight
  int n = blockIdx.x;
  int t = threadIdx.x;
  int slot = t / L;
  int l = t % L;
  int head = (4 * l) >> 6;
  int s0 = row_ptr[n], s1 = row_ptr[n + 1];
  const float4* __restrict__ xh4 = (const float4*)xh;
  float4 acc = make_float4(0.f, 0.f, 0.f, 0.f);
  for (int i = s0 + slot; i < s1; i += S) {
    int s = csr_src[i];
    float w = attn[i * H + head];
    float4 v = xh4[(size_t)s * L + l];
    acc.x += v.x * w;
    acc.y += v.y * w;
    acc.z += v.z * w;
    acc.w += v.w * w;
  }
  __shared__ float4 red[256];
  red[t] = acc;
  __syncthreads();
  if (t < L) {
    float4 a = red[t];
    #pragma unroll
    for (int s = 1; s < S; ++s) {
      float4 b = red[t + s * L];
      a.x += b.x; a.y += b.y; a.z += b.z; a.w += b.w;
    }
    float4 bv = ((const float4*)bias)[l];
    a.x += bv.x; a.y += bv.y; a.z += bv.z; a.w += bv.w;
    if (APPLY_ELU) {
      a.x = elu_f(a.x); a.y = elu_f(a.y); a.z = elu_f(a.z); a.w = elu_f(a.w);
    }
    if (OUT_BF) {
      ushort4 o;
      o.x = bf16_rne(a.x); o.y = bf16_rne(a.y); o.z = bf16_rne(a.z); o.w = bf16_rne(a.w);
      ((ushort4*)out_bf)[(size_t)n * L + l] = o;
    } else {
      ((float4*)out)[(size_t)n * L + l] = a;
    }
  }
}

// ---------------- classifier: wave per node, 64 -> softmax(4) ----------------

__global__ void classifier_kernel(const float* __restrict__ h, const float* __restrict__ Wc,
                                  const float* __restrict__ bc, float* __restrict__ out,
                                  int n_nodes) {
  int gid = blockIdx.x * 256 + threadIdx.x;
  int w = gid >> 6, lane = gid & 63;
  if (w >= n_nodes) return;
  float hv = h[w * 64 + lane];
  float p0 = hv * Wc[lane * 4 + 0];
  float p1 = hv * Wc[lane * 4 + 1];
  float p2 = hv * Wc[lane * 4 + 2];
  float p3 = hv * Wc[lane * 4 + 3];
  for (int off = 32; off; off >>= 1) {
    p0 += __shfl_down(p0, off);
    p1 += __shfl_down(p1, off);
    p2 += __shfl_down(p2, off);
    p3 += __shfl_down(p3, off);
  }
  if (lane == 0) {
    p0 += bc[0]; p1 += bc[1]; p2 += bc[2]; p3 += bc[3];
    float mx = fmaxf(fmaxf(p0, p1), fmaxf(p2, p3));
    float e0 = __expf(p0 - mx), e1 = __expf(p1 - mx), e2 = __expf(p2 - mx), e3 = __expf(p3 - mx);
    float inv = 1.f / (e0 + e1 + e2 + e3);
    out[w * 4 + 0] = e0 * inv;
    out[w * 4 + 1] = e1 * inv;
    out[w * 4 + 2] = e2 * inv;
    out[w * 4 + 3] = e3 * inv;
  }
}

// ---------------- host ----------------

extern "C" void kernel_launch(void* const* d_in, const int* in_sizes, int n_in,
                              void* d_out, int out_size, void* d_ws, size_t ws_size,
                              hipStream_t stream) {
  const float* x   = (const float*)d_in[0];
  const int*   ei  = (const int*)d_in[1];
  const float* ea  = (const float*)d_in[2];
  const float* Wp  = (const float*)d_in[3];
  const float* bp  = (const float*)d_in[4];
  const float* W1  = (const float*)d_in[5];
  const float* We1 = (const float*)d_in[6];
  const float* as1 = (const float*)d_in[7];
  const float* ad1 = (const float*)d_in[8];
  const float* ae1 = (const float*)d_in[9];
  const float* b1  = (const float*)d_in[10];
  const float* W2  = (const float*)d_in[11];
  const float* We2 = (const float*)d_in[12];
  const float* as2 = (const float*)d_in[13];
  const float* ad2 = (const float*)d_in[14];
  const float* ae2 = (const float*)d_in[15];
  const float* b2  = (const float*)d_in[16];
  const float* W3  = (const float*)d_in[17];
  const float* We3 = (const float*)d_in[18];
  const float* as3 = (const float*)d_in[19];
  const float* ad3 = (const float*)d_in[20];
  const float* ae3 = (const float*)d_in[21];
  const float* b3  = (const float*)d_in[22];
  const float* Wc  = (const float*)d_in[23];
  const float* bc  = (const float*)d_in[24];
  float* out = (float*)d_out;

  const int* src = ei;
  const int* dst = ei + N_EDGES;

  char* wptr = (char*)d_ws;
  auto alloc = [&](size_t bytes) {
    char* p = wptr;
    wptr += (bytes + 255) & ~(size_t)255;
    return p;
  };
  int*            cnt      = (int*)alloc((size_t)N_NODES * 4);
  int*            row_ptr  = (int*)alloc((size_t)(N_NODES + 1) * 4);
  int*            row_next = (int*)alloc((size_t)N_NODES * 4);
  int*            csr_src  = (int*)alloc((size_t)N_EDGES * 4);
  int*            csr_dst  = (int*)alloc((size_t)N_EDGES * 4);
  float*          csr_ea   = (float*)alloc((size_t)N_EDGES * 3 * 4);
  unsigned short* hA_bf    = (unsigned short*)alloc((size_t)N_NODES * 256 * 2);
  float*          hB       = (float*)alloc((size_t)N_NODES * 256 * 4);
  float*          hC       = (float*)alloc((size_t)N_NODES * 64 * 4);
  float*          alp_s    = (float*)alloc((size_t)N_NODES * 4 * 4);
  float*          alp_d    = (float*)alloc((size_t)N_NODES * 4 * 4);
  float*          alp_e    = (float*)alloc((size_t)N_EDGES * 4 * 4);
  float2*         stats    = (float2*)alloc((size_t)N_NODES * 4 * 8);
  float*          proj     = (float*)alloc(64);
  unsigned short* Bt1      = (unsigned short*)alloc((size_t)64 * 256 * 2);
  unsigned short* Bt2      = (unsigned short*)alloc((size_t)256 * 256 * 2);
  unsigned short* Bt3      = (unsigned short*)alloc((size_t)256 * 64 * 2);

  // ---- CSR build ----
  zero_int_kernel<<<(N_NODES + 255) / 256, 256, 0, stream>>>(cnt, N_NODES);
  hist_kernel<<<(N_EDGES + 255) / 256, 256, 0, stream>>>(dst, cnt, N_EDGES);
  scan_kernel<<<1, 1024, 0, stream>>>(cnt, row_ptr, row_next, N_NODES);
  fill_kernel<<<(N_EDGES + 255) / 256, 256, 0, stream>>>(src, dst, ea, row_next,
                                                         csr_src, csr_dst, csr_ea, N_EDGES);

  // ---- weight prep (cast + transpose to bf16 [Nc][K]) ----
  wt_bf_kernel<<<(64 * 256 + 255) / 256, 256, 0, stream>>>(W1, Bt1, 64, 256);
  wt_bf_kernel<<<(256 * 256 + 255) / 256, 256, 0, stream>>>(W2, Bt2, 256, 256);
  wt_bf_kernel<<<(256 * 64 + 255) / 256, 256, 0, stream>>>(W3, Bt3, 256, 64);

  // ---- input projection (bf16) ----
  in_proj_kernel<<<N_NODES * 64 / 256, 256, 0, stream>>>(x, Wp, bp, hA_bf, N_NODES);

  dim3 g256(4, (N_NODES + 63) / 64);
  dim3 g64(1, (N_NODES + 63) / 64);

  // ---- layer 1: 64 -> 4 heads x 64, ELU ----
  mfma_gemm_kernel<64><<<g256, 256, 0, stream>>>(hA_bf, Bt1, hB, N_NODES, 256);
  alpha_sd_kernel<<<N_NODES * 4 * 64 / 256, 256, 0, stream>>>(hB, as1, ad1, alp_s, alp_d, N_NODES, 4);
  aeproj_kernel<<<1, 64, 0, stream>>>(We1, ae1, proj, 4);
  alpha_csr_kernel<<<(N_EDGES * 4 + 255) / 256, 256, 0, stream>>>(csr_src, csr_dst, csr_ea,
                                                                  alp_s, alp_d, proj, alp_e,
                                                                  N_EDGES, 4);
  softmax_stats_kernel<4><<<(N_NODES * 4 * 64 + 255) / 256, 256, 0, stream>>>(row_ptr, alp_e, stats, N_NODES);
  attn_norm_kernel<4><<<(N_EDGES * 4 + 255) / 256, 256, 0, stream>>>(csr_dst, stats, alp_e, N_EDGES);
  aggregate_kernel<256, true, true><<<N_NODES, 256, 0, stream>>>(row_ptr, csr_src, alp_e, hB, b1,
                                                                 nullptr, hA_bf);

  // ---- layer 2: 256 -> 4 heads x 64, ELU ----
  mfma_gemm_kernel<256><<<g256, 256, 0, stream>>>(hA_bf, Bt2, hB, N_NODES, 256);
  alpha_sd_kernel<<<N_NODES * 4 * 64 / 256, 256, 0, stream>>>(hB, as2, ad2, alp_s, alp_d, N_NODES, 4);
  aeproj_kernel<<<1, 64, 0, stream>>>(We2, ae2, proj, 4);
  alpha_csr_kernel<<<(N_EDGES * 4 + 255) / 256, 256, 0, stream>>>(csr_src, csr_dst, csr_ea,
                                                                  alp_s, alp_d, proj, alp_e,
                                                                  N_EDGES, 4);
  softmax_stats_kernel<4><<<(N_NODES * 4 * 64 + 255) / 256, 256, 0, stream>>>(row_ptr, alp_e, stats, N_NODES);
  attn_norm_kernel<4><<<(N_EDGES * 4 + 255) / 256, 256, 0, stream>>>(csr_dst, stats, alp_e, N_EDGES);
  aggregate_kernel<256, true, true><<<N_NODES, 256, 0, stream>>>(row_ptr, csr_src, alp_e, hB, b2,
                                                                 nullptr, hA_bf);

  // ---- layer 3: 256 -> 1 head x 64, no ELU ----
  mfma_gemm_kernel<256><<<g64, 256, 0, stream>>>(hA_bf, Bt3, hB, N_NODES, 64);
  alpha_sd_kernel<<<N_NODES * 1 * 64 / 256, 256, 0, stream>>>(hB, as3, ad3, alp_s, alp_d, N_NODES, 1);
  aeproj_kernel<<<1, 64, 0, stream>>>(We3, ae3, proj, 1);
  alpha_csr_kernel<<<(N_EDGES * 1 + 255) / 256, 256, 0, stream>>>(csr_src, csr_dst, csr_ea,
                                                                  alp_s, alp_d, proj, alp_e,
                                                                  N_EDGES, 1);
  softmax_stats_kernel<1><<<(N_NODES * 1 * 64 + 255) / 256, 256, 0, stream>>>(row_ptr, alp_e, stats, N_NODES);
  attn_norm_kernel<1><<<(N_EDGES * 1 + 255) / 256, 256, 0, stream>>>(csr_dst, stats, alp_e, N_EDGES);
  aggregate_kernel<64, false, false><<<N_NODES, 256, 0, stream>>>(row_ptr, csr_src, alp_e, hB, b3,
                                                                  hC, nullptr);

  // ---- classifier + softmax ----
  classifier_kernel<<<N_NODES * 64 / 256, 256, 0, stream>>>(hC, Wc, bc, out, N_NODES);
}

// Round 4
// 465.983 us; speedup vs baseline: 1.7121x; 1.2310x over previous
//
#include <hip/hip_runtime.h>
#include <math.h>

#define N_NODES 20000
#define N_EDGES 640000

typedef __attribute__((ext_vector_type(8))) short short8;
typedef __attribute__((ext_vector_type(4))) float floatx4;

__device__ __forceinline__ float elu_f(float v) { return v > 0.f ? v : expm1f(v); }

__device__ __forceinline__ unsigned short bf16_rne(float f) {
  union { float f; unsigned u; } v;
  v.f = f;
  unsigned r = v.u + 0x7FFF + ((v.u >> 16) & 1);
  return (unsigned short)(r >> 16);
}

__device__ __forceinline__ float bf_to_f(unsigned short u) {
  union { unsigned u; float f; } v;
  v.u = (unsigned)u << 16;
  return v.f;
}

// ---------------- CSR build ----------------

__global__ void zero_int_kernel(int* p, int n) {
  int i = blockIdx.x * 256 + threadIdx.x;
  if (i < n) p[i] = 0;
}

__global__ void hist_kernel(const int* __restrict__ dst, int* __restrict__ cnt, int ne) {
  int e = blockIdx.x * 256 + threadIdx.x;
  if (e < ne) atomicAdd(&cnt[dst[e]], 1);
}

__global__ __launch_bounds__(1024) void scan_kernel(const int* __restrict__ cnt,
                                                    int* __restrict__ row_ptr,
                                                    int* __restrict__ row_next, int n) {
  __shared__ int part[1024];
  int t = threadIdx.x;
  int per = (n + 1023) / 1024;
  int base = t * per;
  int local = 0;
  for (int i = 0; i < per; ++i) {
    int idx = base + i;
    if (idx < n) local += cnt[idx];
  }
  part[t] = local;
  __syncthreads();
  for (int off = 1; off < 1024; off <<= 1) {
    int v = (t >= off) ? part[t - off] : 0;
    __syncthreads();
    part[t] += v;
    __syncthreads();
  }
  int prefix = (t == 0) ? 0 : part[t - 1];
  for (int i = 0; i < per; ++i) {
    int idx = base + i;
    if (idx < n) {
      row_ptr[idx] = prefix;
      row_next[idx] = prefix;
      prefix += cnt[idx];
    }
  }
  if (t == 1023) row_ptr[n] = part[1023];
}

__global__ void fill_kernel(const int* __restrict__ src, const int* __restrict__ dst,
                            const float* __restrict__ ea, int* __restrict__ row_next,
                            int* __restrict__ csr_src, float* __restrict__ csr_ea, int ne) {
  int e = blockIdx.x * 256 + threadIdx.x;
  if (e >= ne) return;
  int d = dst[e];
  int pos = atomicAdd(&row_next[d], 1);
  csr_src[pos] = src[e];
  csr_ea[pos * 3 + 0] = ea[e * 3 + 0];
  csr_ea[pos * 3 + 1] = ea[e * 3 + 1];
  csr_ea[pos * 3 + 2] = ea[e * 3 + 2];
}

// ---------------- weight cast+transpose (all 3 in one): Bt[n][k] = bf16(W[k][n]) ----

__global__ void wt_all_kernel(const float* __restrict__ W1, const float* __restrict__ W2,
                              const float* __restrict__ W3, unsigned short* __restrict__ Bt1,
                              unsigned short* __restrict__ Bt2, unsigned short* __restrict__ Bt3) {
  int idx = blockIdx.x * 256 + threadIdx.x;
  const float* W; unsigned short* Bt; int K, Nc, local;
  if (idx < 16384)      { W = W1; Bt = Bt1; K = 64;  Nc = 256; local = idx; }
  else if (idx < 81920) { W = W2; Bt = Bt2; K = 256; Nc = 256; local = idx - 16384; }
  else if (idx < 98304) { W = W3; Bt = Bt3; K = 256; Nc = 64;  local = idx - 81920; }
  else return;
  int k = local / Nc, n = local - k * Nc;
  Bt[(size_t)n * K + k] = bf16_rne(W[local]);
}

// ---------------- aeproj (all 3 layers): proj[d*H+h] = sum_c We[d, h*64+c]*ae[h*64+c] ----
// layout: proj[0..11] layer1 (3x4), proj[12..23] layer2 (3x4), proj[24..26] layer3 (3x1)

__global__ void aeproj_all_kernel(const float* __restrict__ We1, const float* __restrict__ ae1,
                                  const float* __restrict__ We2, const float* __restrict__ ae2,
                                  const float* __restrict__ We3, const float* __restrict__ ae3,
                                  float* __restrict__ proj) {
  int t = threadIdx.x;
  if (t < 12) {
    int d = t >> 2, h = t & 3;
    float s = 0.f;
    for (int c = 0; c < 64; ++c) s += We1[d * 256 + h * 64 + c] * ae1[h * 64 + c];
    proj[t] = s;
  } else if (t < 24) {
    int u = t - 12; int d = u >> 2, h = u & 3;
    float s = 0.f;
    for (int c = 0; c < 64; ++c) s += We2[d * 256 + h * 64 + c] * ae2[h * 64 + c];
    proj[t] = s;
  } else if (t < 27) {
    int d = t - 24;
    float s = 0.f;
    for (int c = 0; c < 64; ++c) s += We3[d * 64 + c] * ae3[c];
    proj[t] = s;
  }
}

// ---------------- input projection (emit bf16) ----------------

__global__ void in_proj_kernel(const float* __restrict__ x, const float* __restrict__ Wp,
                               const float* __restrict__ bp, unsigned short* __restrict__ h_bf,
                               int n) {
  int i = blockIdx.x * 256 + threadIdx.x;
  if (i >= n * 64) return;
  int node = i >> 6, c = i & 63;
  float v = x[node * 2] * Wp[c] + x[node * 2 + 1] * Wp[64 + c] + bp[c];
  h_bf[i] = bf16_rne(elu_f(v));
}

// ---------------- MFMA bf16 GEMM: C_bf[M,Nc] = A[M,K] @ Bt[Nc,K]^T, bf16 out ----------

template <int KDIM>
__global__ __launch_bounds__(256) void mfma_gemm_kernel(const unsigned short* __restrict__ A,
                                                        const unsigned short* __restrict__ Bt,
                                                        unsigned short* __restrict__ C_bf,
                                                        int M, int Nc) {
  __shared__ unsigned short As[64][40];
  __shared__ unsigned short Bs[64][40];
  int t = threadIdx.x;
  int wave = t >> 6, lane = t & 63;
  int m_frag = lane & 15, quad = lane >> 4;
  int row0 = blockIdx.y * 64, col0 = blockIdx.x * 64;
  int lr = t >> 2;
  int lk = (t & 3) * 8;
  floatx4 acc[4];
  #pragma unroll
  for (int c = 0; c < 4; ++c) acc[c] = (floatx4){0.f, 0.f, 0.f, 0.f};

  for (int k0 = 0; k0 < KDIM; k0 += 32) {
    int gr = row0 + lr;
    short8 av = {0, 0, 0, 0, 0, 0, 0, 0};
    if (gr < M) av = *(const short8*)(A + (size_t)gr * KDIM + k0 + lk);
    *(short8*)(&As[lr][lk]) = av;
    short8 bv = *(const short8*)(Bt + (size_t)(col0 + lr) * KDIM + k0 + lk);
    *(short8*)(&Bs[lr][lk]) = bv;
    __syncthreads();
    short8 a = *(const short8*)(&As[wave * 16 + m_frag][quad * 8]);
    #pragma unroll
    for (int c = 0; c < 4; ++c) {
      short8 b = *(const short8*)(&Bs[c * 16 + m_frag][quad * 8]);
      acc[c] = __builtin_amdgcn_mfma_f32_16x16x32_bf16(a, b, acc[c], 0, 0, 0);
    }
    __syncthreads();
  }
  #pragma unroll
  for (int c = 0; c < 4; ++c) {
    #pragma unroll
    for (int i = 0; i < 4; ++i) {
      int gr = row0 + wave * 16 + quad * 4 + i;
      if (gr < M) C_bf[(size_t)gr * Nc + col0 + c * 16 + m_frag] = bf16_rne(acc[c][i]);
    }
  }
}

// ---------------- alpha_src / alpha_dst from bf16 xh: wave per (n,h) ----------------

__global__ void alpha_sd_kernel(const unsigned short* __restrict__ xh_bf,
                                const float* __restrict__ a_s, const float* __restrict__ a_d,
                                float* __restrict__ alpha_s, float* __restrict__ alpha_d,
                                int n_nodes, int heads) {
  int gid = blockIdx.x * 256 + threadIdx.x;
  int wid = gid >> 6, lane = gid & 63;
  if (wid >= n_nodes * heads) return;
  int h = wid % heads;
  float v = bf_to_f(xh_bf[(size_t)wid * 64 + lane]);
  float ps = v * a_s[h * 64 + lane];
  float pd = v * a_d[h * 64 + lane];
  for (int off = 32; off; off >>= 1) {
    ps += __shfl_down(ps, off);
    pd += __shfl_down(pd, off);
  }
  if (lane == 0) {
    alpha_s[wid] = ps;
    alpha_d[wid] = pd;
  }
}

// ---------------- fused per-node alpha + segment-softmax, planes [H][E] -------------
// H==4: block = node, wave = head.  H==1: block = 4 nodes, wave = node.

template <int H>
__global__ __launch_bounds__(256) void fused_softmax_kernel(const int* __restrict__ row_ptr,
                                                            const int* __restrict__ csr_src,
                                                            const float* __restrict__ csr_ea,
                                                            const float* __restrict__ alp_s,
                                                            const float* __restrict__ alp_d,
                                                            const float* __restrict__ proj,
                                                            float* __restrict__ attn,
                                                            int n_nodes) {
  int t = threadIdx.x;
  int wave = t >> 6, lane = t & 63;
  int n, h;
  if (H == 4) { n = blockIdx.x; h = wave; }
  else        { n = blockIdx.x * 4 + wave; h = 0; if (n >= n_nodes) return; }
  int s0 = row_ptr[n], s1 = row_ptr[n + 1];
  float adv = alp_d[n * H + h];
  float p0 = proj[0 * H + h], p1 = proj[1 * H + h], p2 = proj[2 * H + h];
  float* __restrict__ plane = attn + (size_t)h * N_EDGES;
  float m = -INFINITY, ssum = 0.f;
  for (int i = s0 + lane; i < s1; i += 64) {
    int s = csr_src[i];
    float a = alp_s[s * H + h] + adv
            + csr_ea[i * 3 + 0] * p0 + csr_ea[i * 3 + 1] * p1 + csr_ea[i * 3 + 2] * p2;
    a = a > 0.f ? a : 0.2f * a;
    plane[i] = a;
    float nm = fmaxf(m, a);
    ssum = ssum * __expf(m - nm) + __expf(a - nm);
    m = nm;
  }
  #pragma unroll
  for (int off = 1; off < 64; off <<= 1) {
    float mo = __shfl_xor(m, off);
    float so = __shfl_xor(ssum, off);
    float nm = fmaxf(m, mo);
    if (nm > -INFINITY) {
      ssum = ssum * __expf(m - nm) + so * __expf(mo - nm);
      m = nm;
    }
  }
  float inv = 1.0f / (ssum + 1e-16f);
  for (int i = s0 + lane; i < s1; i += 64) {
    plane[i] = __expf(plane[i] - m) * inv;
  }
}

// ---------------- aggregation from bf16 xh, attn planes ----------------
// HC=256: slot=t>>5 (8 slots), l=t&31 (8 channels each), head=l>>3
// HC=64:  slot=t>>3 (32 slots), l=t&7,  head=0

template <int HC, bool APPLY_ELU, bool OUT_BF>
__global__ __launch_bounds__(256) void aggregate_kernel(const int* __restrict__ row_ptr,
                                                        const int* __restrict__ csr_src,
                                                        const float* __restrict__ attn,
                                                        const unsigned short* __restrict__ xh_bf,
                                                        const float* __restrict__ bias,
                                                        float* __restrict__ out,
                                                        unsigned short* __restrict__ out_bf) {
  constexpr int L = HC / 8;    // lanes per edge slot
  constexpr int S = 256 / L;   // edge slots
  int n = blockIdx.x;
  int t = threadIdx.x;
  int slot = t / L;
  int l = t % L;
  int head = (8 * l) >> 6;
  int s0 = row_ptr[n], s1 = row_ptr[n + 1];
  const float* __restrict__ attn_h = attn + (size_t)head * N_EDGES;
  float acc[8] = {};
  for (int i = s0 + slot; i < s1; i += S) {
    int s = csr_src[i];
    float w = attn_h[i];
    short8 v = *(const short8*)(xh_bf + (size_t)s * HC + l * 8);
    #pragma unroll
    for (int j = 0; j < 8; ++j) acc[j] += bf_to_f((unsigned short)v[j]) * w;
  }
  __shared__ float red[S * HC];
  #pragma unroll
  for (int j = 0; j < 8; ++j) red[slot * HC + l * 8 + j] = acc[j];
  __syncthreads();
  if (t < HC) {
    float a = 0.f;
    #pragma unroll
    for (int s = 0; s < S; ++s) a += red[s * HC + t];
    a += bias[t];
    if (APPLY_ELU) a = elu_f(a);
    if (OUT_BF) out_bf[(size_t)n * HC + t] = bf16_rne(a);
    else        out[(size_t)n * HC + t] = a;
  }
}

// ---------------- classifier: wave per node, 64 -> softmax(4) ----------------

__global__ void classifier_kernel(const float* __restrict__ h, const float* __restrict__ Wc,
                                  const float* __restrict__ bc, float* __restrict__ out,
                                  int n_nodes) {
  int gid = blockIdx.x * 256 + threadIdx.x;
  int w = gid >> 6, lane = gid & 63;
  if (w >= n_nodes) return;
  float hv = h[w * 64 + lane];
  float p0 = hv * Wc[lane * 4 + 0];
  float p1 = hv * Wc[lane * 4 + 1];
  float p2 = hv * Wc[lane * 4 + 2];
  float p3 = hv * Wc[lane * 4 + 3];
  for (int off = 32; off; off >>= 1) {
    p0 += __shfl_down(p0, off);
    p1 += __shfl_down(p1, off);
    p2 += __shfl_down(p2, off);
    p3 += __shfl_down(p3, off);
  }
  if (lane == 0) {
    p0 += bc[0]; p1 += bc[1]; p2 += bc[2]; p3 += bc[3];
    float mx = fmaxf(fmaxf(p0, p1), fmaxf(p2, p3));
    float e0 = __expf(p0 - mx), e1 = __expf(p1 - mx), e2 = __expf(p2 - mx), e3 = __expf(p3 - mx);
    float inv = 1.f / (e0 + e1 + e2 + e3);
    out[w * 4 + 0] = e0 * inv;
    out[w * 4 + 1] = e1 * inv;
    out[w * 4 + 2] = e2 * inv;
    out[w * 4 + 3] = e3 * inv;
  }
}

// ---------------- host ----------------

extern "C" void kernel_launch(void* const* d_in, const int* in_sizes, int n_in,
                              void* d_out, int out_size, void* d_ws, size_t ws_size,
                              hipStream_t stream) {
  const float* x   = (const float*)d_in[0];
  const int*   ei  = (const int*)d_in[1];
  const float* ea  = (const float*)d_in[2];
  const float* Wp  = (const float*)d_in[3];
  const float* bp  = (const float*)d_in[4];
  const float* W1  = (const float*)d_in[5];
  const float* We1 = (const float*)d_in[6];
  const float* as1 = (const float*)d_in[7];
  const float* ad1 = (const float*)d_in[8];
  const float* ae1 = (const float*)d_in[9];
  const float* b1  = (const float*)d_in[10];
  const float* W2  = (const float*)d_in[11];
  const float* We2 = (const float*)d_in[12];
  const float* as2 = (const float*)d_in[13];
  const float* ad2 = (const float*)d_in[14];
  const float* ae2 = (const float*)d_in[15];
  const float* b2  = (const float*)d_in[16];
  const float* W3  = (const float*)d_in[17];
  const float* We3 = (const float*)d_in[18];
  const float* as3 = (const float*)d_in[19];
  const float* ad3 = (const float*)d_in[20];
  const float* ae3 = (const float*)d_in[21];
  const float* b3  = (const float*)d_in[22];
  const float* Wc  = (const float*)d_in[23];
  const float* bc  = (const float*)d_in[24];
  float* out = (float*)d_out;

  const int* src = ei;
  const int* dst = ei + N_EDGES;

  char* wptr = (char*)d_ws;
  auto alloc = [&](size_t bytes) {
    char* p = wptr;
    wptr += (bytes + 255) & ~(size_t)255;
    return p;
  };
  int*            cnt      = (int*)alloc((size_t)N_NODES * 4);
  int*            row_ptr  = (int*)alloc((size_t)(N_NODES + 1) * 4);
  int*            row_next = (int*)alloc((size_t)N_NODES * 4);
  int*            csr_src  = (int*)alloc((size_t)N_EDGES * 4);
  float*          csr_ea   = (float*)alloc((size_t)N_EDGES * 3 * 4);
  unsigned short* hA_bf    = (unsigned short*)alloc((size_t)N_NODES * 256 * 2);
  unsigned short* hX_bf    = (unsigned short*)alloc((size_t)N_NODES * 256 * 2);
  float*          hC       = (float*)alloc((size_t)N_NODES * 64 * 4);
  float*          alp_s    = (float*)alloc((size_t)N_NODES * 4 * 4);
  float*          alp_d    = (float*)alloc((size_t)N_NODES * 4 * 4);
  float*          alp_e    = (float*)alloc((size_t)N_EDGES * 4 * 4);   // [H][E] planes
  float*          proj     = (float*)alloc(32 * 4);
  unsigned short* Bt1      = (unsigned short*)alloc((size_t)64 * 256 * 2);
  unsigned short* Bt2      = (unsigned short*)alloc((size_t)256 * 256 * 2);
  unsigned short* Bt3      = (unsigned short*)alloc((size_t)256 * 64 * 2);

  // ---- CSR build ----
  zero_int_kernel<<<(N_NODES + 255) / 256, 256, 0, stream>>>(cnt, N_NODES);
  hist_kernel<<<(N_EDGES + 255) / 256, 256, 0, stream>>>(dst, cnt, N_EDGES);
  scan_kernel<<<1, 1024, 0, stream>>>(cnt, row_ptr, row_next, N_NODES);
  fill_kernel<<<(N_EDGES + 255) / 256, 256, 0, stream>>>(src, dst, ea, row_next,
                                                         csr_src, csr_ea, N_EDGES);

  // ---- weight & edge-proj prep ----
  wt_all_kernel<<<(98304 + 255) / 256, 256, 0, stream>>>(W1, W2, W3, Bt1, Bt2, Bt3);
  aeproj_all_kernel<<<1, 64, 0, stream>>>(We1, ae1, We2, ae2, We3, ae3, proj);

  // ---- input projection (bf16) ----
  in_proj_kernel<<<N_NODES * 64 / 256, 256, 0, stream>>>(x, Wp, bp, hA_bf, N_NODES);

  dim3 g256(4, (N_NODES + 63) / 64);
  dim3 g64(1, (N_NODES + 63) / 64);

  // ---- layer 1: 64 -> 4x64, ELU ----
  mfma_gemm_kernel<64><<<g256, 256, 0, stream>>>(hA_bf, Bt1, hX_bf, N_NODES, 256);
  alpha_sd_kernel<<<N_NODES * 4 * 64 / 256, 256, 0, stream>>>(hX_bf, as1, ad1, alp_s, alp_d, N_NODES, 4);
  fused_softmax_kernel<4><<<N_NODES, 256, 0, stream>>>(row_ptr, csr_src, csr_ea, alp_s, alp_d,
                                                       proj + 0, alp_e, N_NODES);
  aggregate_kernel<256, true, true><<<N_NODES, 256, 0, stream>>>(row_ptr, csr_src, alp_e, hX_bf,
                                                                 b1, nullptr, hA_bf);

  // ---- layer 2: 256 -> 4x64, ELU ----
  mfma_gemm_kernel<256><<<g256, 256, 0, stream>>>(hA_bf, Bt2, hX_bf, N_NODES, 256);
  alpha_sd_kernel<<<N_NODES * 4 * 64 / 256, 256, 0, stream>>>(hX_bf, as2, ad2, alp_s, alp_d, N_NODES, 4);
  fused_softmax_kernel<4><<<N_NODES, 256, 0, stream>>>(row_ptr, csr_src, csr_ea, alp_s, alp_d,
                                                       proj + 12, alp_e, N_NODES);
  aggregate_kernel<256, true, true><<<N_NODES, 256, 0, stream>>>(row_ptr, csr_src, alp_e, hX_bf,
                                                                 b2, nullptr, hA_bf);

  // ---- layer 3: 256 -> 1x64, no ELU ----
  mfma_gemm_kernel<256><<<g64, 256, 0, stream>>>(hA_bf, Bt3, hX_bf, N_NODES, 64);
  alpha_sd_kernel<<<N_NODES * 1 * 64 / 256, 256, 0, stream>>>(hX_bf, as3, ad3, alp_s, alp_d, N_NODES, 1);
  fused_softmax_kernel<1><<<(N_NODES + 3) / 4, 256, 0, stream>>>(row_ptr, csr_src, csr_ea, alp_s,
                                                                 alp_d, proj + 24, alp_e, N_NODES);
  aggregate_kernel<64, false, false><<<N_NODES, 256, 0, stream>>>(row_ptr, csr_src, alp_e, hX_bf,
                                                                  b3, hC, nullptr);

  // ---- classifier + softmax ----
  classifier_kernel<<<N_NODES * 64 / 256, 256, 0, stream>>>(hC, Wc, bc, out, N_NODES);
}

// Round 5
// 423.214 us; speedup vs baseline: 1.8851x; 1.1011x over previous
//
#include <hip/hip_runtime.h>
#include <math.h>

#define N_NODES 20000
#define N_EDGES 640000

typedef __attribute__((ext_vector_type(8))) short short8;
typedef __attribute__((ext_vector_type(4))) float floatx4;

__device__ __forceinline__ float elu_f(float v) { return v > 0.f ? v : expm1f(v); }

__device__ __forceinline__ unsigned short bf16_rne(float f) {
  union { float f; unsigned u; } v;
  v.f = f;
  unsigned r = v.u + 0x7FFF + ((v.u >> 16) & 1);
  return (unsigned short)(r >> 16);
}

__device__ __forceinline__ float bf_to_f(unsigned short u) {
  union { unsigned u; float f; } v;
  v.u = (unsigned)u << 16;
  return v.f;
}

// ---------------- CSR build ----------------

__global__ void zero_int_kernel(int* p, int n) {
  int i = blockIdx.x * 256 + threadIdx.x;
  if (i < n) p[i] = 0;
}

__global__ void hist_kernel(const int* __restrict__ dst, int* __restrict__ cnt, int ne) {
  int e = blockIdx.x * 256 + threadIdx.x;
  if (e < ne) atomicAdd(&cnt[dst[e]], 1);
}

__global__ __launch_bounds__(1024) void scan_kernel(const int* __restrict__ cnt,
                                                    int* __restrict__ row_ptr,
                                                    int* __restrict__ row_next, int n) {
  __shared__ int part[1024];
  int t = threadIdx.x;
  int per = (n + 1023) / 1024;
  int base = t * per;
  int local = 0;
  for (int i = 0; i < per; ++i) {
    int idx = base + i;
    if (idx < n) local += cnt[idx];
  }
  part[t] = local;
  __syncthreads();
  for (int off = 1; off < 1024; off <<= 1) {
    int v = (t >= off) ? part[t - off] : 0;
    __syncthreads();
    part[t] += v;
    __syncthreads();
  }
  int prefix = (t == 0) ? 0 : part[t - 1];
  for (int i = 0; i < per; ++i) {
    int idx = base + i;
    if (idx < n) {
      row_ptr[idx] = prefix;
      row_next[idx] = prefix;
      prefix += cnt[idx];
    }
  }
  if (t == 1023) row_ptr[n] = part[1023];
}

// scatter ONLY the edge id (4 B) — consumers gather src/ea through it.
__global__ void fill_kernel(const int* __restrict__ dst, int* __restrict__ row_next,
                            int* __restrict__ csr_eid, int ne) {
  int e = blockIdx.x * 256 + threadIdx.x;
  if (e >= ne) return;
  int pos = atomicAdd(&row_next[dst[e]], 1);
  csr_eid[pos] = e;
}

// ---------------- weight cast+transpose (all 3 in one): Bt[n][k] = bf16(W[k][n]) ----

__global__ void wt_all_kernel(const float* __restrict__ W1, const float* __restrict__ W2,
                              const float* __restrict__ W3, unsigned short* __restrict__ Bt1,
                              unsigned short* __restrict__ Bt2, unsigned short* __restrict__ Bt3) {
  int idx = blockIdx.x * 256 + threadIdx.x;
  const float* W; unsigned short* Bt; int K, Nc, local;
  if (idx < 16384)      { W = W1; Bt = Bt1; K = 64;  Nc = 256; local = idx; }
  else if (idx < 81920) { W = W2; Bt = Bt2; K = 256; Nc = 256; local = idx - 16384; }
  else if (idx < 98304) { W = W3; Bt = Bt3; K = 256; Nc = 64;  local = idx - 81920; }
  else return;
  int k = local / Nc, n = local - k * Nc;
  Bt[(size_t)n * K + k] = bf16_rne(W[local]);
}

// ---------------- aeproj (all 3 layers) -----------------------------------------
// proj[0..11] layer1 (d*4+h), proj[12..23] layer2, proj[24..26] layer3

__global__ void aeproj_all_kernel(const float* __restrict__ We1, const float* __restrict__ ae1,
                                  const float* __restrict__ We2, const float* __restrict__ ae2,
                                  const float* __restrict__ We3, const float* __restrict__ ae3,
                                  float* __restrict__ proj) {
  int t = threadIdx.x;
  if (t < 12) {
    int d = t >> 2, h = t & 3;
    float s = 0.f;
    for (int c = 0; c < 64; ++c) s += We1[d * 256 + h * 64 + c] * ae1[h * 64 + c];
    proj[t] = s;
  } else if (t < 24) {
    int u = t - 12; int d = u >> 2, h = u & 3;
    float s = 0.f;
    for (int c = 0; c < 64; ++c) s += We2[d * 256 + h * 64 + c] * ae2[h * 64 + c];
    proj[t] = s;
  } else if (t < 27) {
    int d = t - 24;
    float s = 0.f;
    for (int c = 0; c < 64; ++c) s += We3[d * 64 + c] * ae3[c];
    proj[t] = s;
  }
}

// ---------------- input projection (emit bf16) ----------------

__global__ void in_proj_kernel(const float* __restrict__ x, const float* __restrict__ Wp,
                               const float* __restrict__ bp, unsigned short* __restrict__ h_bf,
                               int n) {
  int i = blockIdx.x * 256 + threadIdx.x;
  if (i >= n * 64) return;
  int node = i >> 6, c = i & 63;
  float v = x[node * 2] * Wp[c] + x[node * 2 + 1] * Wp[64 + c] + bp[c];
  h_bf[i] = bf16_rne(elu_f(v));
}

// ---------------- MFMA bf16 GEMM + fused alpha_src/alpha_dst epilogue ---------------
// C_bf[M,Nc] = A[M,K] @ Bt[Nc,K]^T (bf16 out). Col-block == head (64 channels),
// so the a_src/a_dst dot reduces across the 16 m_frag lanes of each wave.

template <int KDIM>
__global__ __launch_bounds__(256) void mfma_gemm_alpha_kernel(
    const unsigned short* __restrict__ A, const unsigned short* __restrict__ Bt,
    unsigned short* __restrict__ C_bf, const float* __restrict__ a_src,
    const float* __restrict__ a_dst, float* __restrict__ alp_s,
    float* __restrict__ alp_d, int M, int Nc) {
  __shared__ unsigned short As[64][40];
  __shared__ unsigned short Bs[64][40];
  int t = threadIdx.x;
  int wave = t >> 6, lane = t & 63;
  int m_frag = lane & 15, quad = lane >> 4;
  int row0 = blockIdx.y * 64, col0 = blockIdx.x * 64;
  int lr = t >> 2;
  int lk = (t & 3) * 8;
  floatx4 acc[4];
  #pragma unroll
  for (int c = 0; c < 4; ++c) acc[c] = (floatx4){0.f, 0.f, 0.f, 0.f};

  for (int k0 = 0; k0 < KDIM; k0 += 32) {
    int gr = row0 + lr;
    short8 av = {0, 0, 0, 0, 0, 0, 0, 0};
    if (gr < M) av = *(const short8*)(A + (size_t)gr * KDIM + k0 + lk);
    *(short8*)(&As[lr][lk]) = av;
    short8 bv = *(const short8*)(Bt + (size_t)(col0 + lr) * KDIM + k0 + lk);
    *(short8*)(&Bs[lr][lk]) = bv;
    __syncthreads();
    short8 a = *(const short8*)(&As[wave * 16 + m_frag][quad * 8]);
    #pragma unroll
    for (int c = 0; c < 4; ++c) {
      short8 b = *(const short8*)(&Bs[c * 16 + m_frag][quad * 8]);
      acc[c] = __builtin_amdgcn_mfma_f32_16x16x32_bf16(a, b, acc[c], 0, 0, 0);
    }
    __syncthreads();
  }

  int H = Nc >> 6;
  int head = blockIdx.x;
  float ps[4] = {}, pd[4] = {};
  #pragma unroll
  for (int c = 0; c < 4; ++c) {
    float asv = a_src[head * 64 + c * 16 + m_frag];
    float adv = a_dst[head * 64 + c * 16 + m_frag];
    #pragma unroll
    for (int i = 0; i < 4; ++i) {
      ps[i] += acc[c][i] * asv;
      pd[i] += acc[c][i] * adv;
    }
  }
  #pragma unroll
  for (int off = 1; off < 16; off <<= 1) {
    #pragma unroll
    for (int i = 0; i < 4; ++i) {
      ps[i] += __shfl_xor(ps[i], off);
      pd[i] += __shfl_xor(pd[i], off);
    }
  }
  #pragma unroll
  for (int c = 0; c < 4; ++c) {
    #pragma unroll
    for (int i = 0; i < 4; ++i) {
      int gr = row0 + wave * 16 + quad * 4 + i;
      if (gr < M) C_bf[(size_t)gr * Nc + col0 + c * 16 + m_frag] = bf16_rne(acc[c][i]);
    }
  }
  if (m_frag == 0) {
    #pragma unroll
    for (int i = 0; i < 4; ++i) {
      int gr = row0 + wave * 16 + quad * 4 + i;
      if (gr < M) {
        alp_s[gr * H + head] = ps[i];
        alp_d[gr * H + head] = pd[i];
      }
    }
  }
}

// ---------------- fused softmax + aggregate: one block per dst node -----------------
// Phase 1 (wave h): compute alpha for chunk of <=256 edges into LDS, flash-style
// online (m,s) update. Phase 2 (all): rescale acc, gather xh rows weighted.

template <int HC, bool APPLY_ELU, bool OUT_BF>
__global__ __launch_bounds__(256) void softagg_kernel(
    const int* __restrict__ row_ptr, const int* __restrict__ csr_eid,
    const int* __restrict__ src_arr, const float* __restrict__ ea,
    const float* __restrict__ alp_s, const float* __restrict__ alp_d,
    const float* __restrict__ proj, const unsigned short* __restrict__ xh_bf,
    const float* __restrict__ bias, float* __restrict__ out,
    unsigned short* __restrict__ out_bf) {
  constexpr int H = HC / 64;   // heads
  constexpr int CHUNK = 256;   // edges per LDS chunk (avg degree 32 -> one chunk)
  constexpr int L = HC / 8;    // threads per edge slot (8 channels each)
  constexpr int S = 256 / L;   // edge slots in flight
  __shared__ float lds_w[H][CHUNK];
  __shared__ int lds_src[CHUNK];
  __shared__ float sh_r[H];
  __shared__ float sh_inv[H];
  __shared__ float red[S * HC];

  int n = blockIdx.x;
  int t = threadIdx.x;
  int wave = t >> 6, lane = t & 63;
  int slot = t / L, l = t % L;
  int head2 = (8 * l) >> 6;
  int s0 = row_ptr[n], s1 = row_ptr[n + 1];

  float m_run = -INFINITY, s_run = 0.f;
  float acc[8] = {};
  float adv = 0.f, p0 = 0.f, p1 = 0.f, p2 = 0.f;
  if (wave < H) {
    adv = alp_d[n * H + wave];
    p0 = proj[0 * H + wave];
    p1 = proj[1 * H + wave];
    p2 = proj[2 * H + wave];
  }

  for (int c0 = s0; c0 < s1; c0 += CHUNK) {
    int cend = min(s1, c0 + CHUNK);
    if (wave < H) {
      int h = wave;
      float cm = -INFINITY;
      for (int i = c0 + lane; i < cend; i += 64) {
        int eid = csr_eid[i];
        int s = src_arr[eid];
        if (h == 0) lds_src[i - c0] = s;
        float a = alp_s[s * H + h] + adv
                + ea[eid * 3 + 0] * p0 + ea[eid * 3 + 1] * p1 + ea[eid * 3 + 2] * p2;
        a = a > 0.f ? a : 0.2f * a;
        lds_w[h][i - c0] = a;
        cm = fmaxf(cm, a);
      }
      #pragma unroll
      for (int off = 1; off < 64; off <<= 1) cm = fmaxf(cm, __shfl_xor(cm, off));
      float m_new = fmaxf(m_run, cm);     // chunk non-empty -> finite
      float r = __expf(m_run - m_new);    // first chunk: exp(-inf) = 0
      float se = 0.f;
      for (int i = c0 + lane; i < cend; i += 64) {
        float w = __expf(lds_w[h][i - c0] - m_new);
        lds_w[h][i - c0] = w;
        se += w;
      }
      #pragma unroll
      for (int off = 1; off < 64; off <<= 1) se += __shfl_xor(se, off);
      s_run = s_run * r + se;
      m_run = m_new;
      if (lane == 0) sh_r[h] = r;
    }
    __syncthreads();
    float rr = sh_r[head2];
    #pragma unroll
    for (int j = 0; j < 8; ++j) acc[j] *= rr;
    for (int i = c0 + slot; i < cend; i += S) {
      float w = lds_w[head2][i - c0];
      int s = lds_src[i - c0];
      short8 v = *(const short8*)(xh_bf + (size_t)s * HC + l * 8);
      #pragma unroll
      for (int j = 0; j < 8; ++j) acc[j] += bf_to_f((unsigned short)v[j]) * w;
    }
    __syncthreads();
  }
  if (wave < H && lane == 0) sh_inv[wave] = 1.0f / (s_run + 1e-16f);
  __syncthreads();
  float inv = sh_inv[head2];
  #pragma unroll
  for (int j = 0; j < 8; ++j) red[slot * HC + l * 8 + j] = acc[j] * inv;
  __syncthreads();
  if (t < HC) {
    float a = 0.f;
    #pragma unroll
    for (int s = 0; s < S; ++s) a += red[s * HC + t];
    a += bias[t];
    if (APPLY_ELU) a = elu_f(a);
    if (OUT_BF) out_bf[(size_t)n * HC + t] = bf16_rne(a);
    else out[(size_t)n * HC + t] = a;
  }
}

// ---------------- classifier: wave per node, 64 -> softmax(4) ----------------

__global__ void classifier_kernel(const float* __restrict__ h, const float* __restrict__ Wc,
                                  const float* __restrict__ bc, float* __restrict__ out,
                                  int n_nodes) {
  int gid = blockIdx.x * 256 + threadIdx.x;
  int w = gid >> 6, lane = gid & 63;
  if (w >= n_nodes) return;
  float hv = h[w * 64 + lane];
  float p0 = hv * Wc[lane * 4 + 0];
  float p1 = hv * Wc[lane * 4 + 1];
  float p2 = hv * Wc[lane * 4 + 2];
  float p3 = hv * Wc[lane * 4 + 3];
  for (int off = 32; off; off >>= 1) {
    p0 += __shfl_down(p0, off);
    p1 += __shfl_down(p1, off);
    p2 += __shfl_down(p2, off);
    p3 += __shfl_down(p3, off);
  }
  if (lane == 0) {
    p0 += bc[0]; p1 += bc[1]; p2 += bc[2]; p3 += bc[3];
    float mx = fmaxf(fmaxf(p0, p1), fmaxf(p2, p3));
    float e0 = __expf(p0 - mx), e1 = __expf(p1 - mx), e2 = __expf(p2 - mx), e3 = __expf(p3 - mx);
    float inv = 1.f / (e0 + e1 + e2 + e3);
    out[w * 4 + 0] = e0 * inv;
    out[w * 4 + 1] = e1 * inv;
    out[w * 4 + 2] = e2 * inv;
    out[w * 4 + 3] = e3 * inv;
  }
}

// ---------------- host ----------------

extern "C" void kernel_launch(void* const* d_in, const int* in_sizes, int n_in,
                              void* d_out, int out_size, void* d_ws, size_t ws_size,
                              hipStream_t stream) {
  const float* x   = (const float*)d_in[0];
  const int*   ei  = (const int*)d_in[1];
  const float* ea  = (const float*)d_in[2];
  const float* Wp  = (const float*)d_in[3];
  const float* bp  = (const float*)d_in[4];
  const float* W1  = (const float*)d_in[5];
  const float* We1 = (const float*)d_in[6];
  const float* as1 = (const float*)d_in[7];
  const float* ad1 = (const float*)d_in[8];
  const float* ae1 = (const float*)d_in[9];
  const float* b1  = (const float*)d_in[10];
  const float* W2  = (const float*)d_in[11];
  const float* We2 = (const float*)d_in[12];
  const float* as2 = (const float*)d_in[13];
  const float* ad2 = (const float*)d_in[14];
  const float* ae2 = (const float*)d_in[15];
  const float* b2  = (const float*)d_in[16];
  const float* W3  = (const float*)d_in[17];
  const float* We3 = (const float*)d_in[18];
  const float* as3 = (const float*)d_in[19];
  const float* ad3 = (const float*)d_in[20];
  const float* ae3 = (const float*)d_in[21];
  const float* b3  = (const float*)d_in[22];
  const float* Wc  = (const float*)d_in[23];
  const float* bc  = (const float*)d_in[24];
  float* out = (float*)d_out;

  const int* src = ei;
  const int* dst = ei + N_EDGES;

  char* wptr = (char*)d_ws;
  auto alloc = [&](size_t bytes) {
    char* p = wptr;
    wptr += (bytes + 255) & ~(size_t)255;
    return p;
  };
  int*            cnt      = (int*)alloc((size_t)N_NODES * 4);
  int*            row_ptr  = (int*)alloc((size_t)(N_NODES + 1) * 4);
  int*            row_next = (int*)alloc((size_t)N_NODES * 4);
  int*            csr_eid  = (int*)alloc((size_t)N_EDGES * 4);
  unsigned short* hA_bf    = (unsigned short*)alloc((size_t)N_NODES * 256 * 2);
  unsigned short* hX_bf    = (unsigned short*)alloc((size_t)N_NODES * 256 * 2);
  float*          hC       = (float*)alloc((size_t)N_NODES * 64 * 4);
  float*          alp_s    = (float*)alloc((size_t)N_NODES * 4 * 4);
  float*          alp_d    = (float*)alloc((size_t)N_NODES * 4 * 4);
  float*          proj     = (float*)alloc(32 * 4);
  unsigned short* Bt1      = (unsigned short*)alloc((size_t)64 * 256 * 2);
  unsigned short* Bt2      = (unsigned short*)alloc((size_t)256 * 256 * 2);
  unsigned short* Bt3      = (unsigned short*)alloc((size_t)256 * 64 * 2);

  // ---- CSR build (eid-only scatter) ----
  zero_int_kernel<<<(N_NODES + 255) / 256, 256, 0, stream>>>(cnt, N_NODES);
  hist_kernel<<<(N_EDGES + 255) / 256, 256, 0, stream>>>(dst, cnt, N_EDGES);
  scan_kernel<<<1, 1024, 0, stream>>>(cnt, row_ptr, row_next, N_NODES);
  fill_kernel<<<(N_EDGES + 255) / 256, 256, 0, stream>>>(dst, row_next, csr_eid, N_EDGES);

  // ---- weight & edge-proj prep ----
  wt_all_kernel<<<(98304 + 255) / 256, 256, 0, stream>>>(W1, W2, W3, Bt1, Bt2, Bt3);
  aeproj_all_kernel<<<1, 64, 0, stream>>>(We1, ae1, We2, ae2, We3, ae3, proj);

  // ---- input projection (bf16) ----
  in_proj_kernel<<<N_NODES * 64 / 256, 256, 0, stream>>>(x, Wp, bp, hA_bf, N_NODES);

  dim3 g256(4, (N_NODES + 63) / 64);
  dim3 g64(1, (N_NODES + 63) / 64);

  // ---- layer 1: 64 -> 4x64, ELU ----
  mfma_gemm_alpha_kernel<64><<<g256, 256, 0, stream>>>(hA_bf, Bt1, hX_bf, as1, ad1,
                                                       alp_s, alp_d, N_NODES, 256);
  softagg_kernel<256, true, true><<<N_NODES, 256, 0, stream>>>(row_ptr, csr_eid, src, ea,
                                                               alp_s, alp_d, proj + 0, hX_bf,
                                                               b1, nullptr, hA_bf);

  // ---- layer 2: 256 -> 4x64, ELU ----
  mfma_gemm_alpha_kernel<256><<<g256, 256, 0, stream>>>(hA_bf, Bt2, hX_bf, as2, ad2,
                                                        alp_s, alp_d, N_NODES, 256);
  softagg_kernel<256, true, true><<<N_NODES, 256, 0, stream>>>(row_ptr, csr_eid, src, ea,
                                                               alp_s, alp_d, proj + 12, hX_bf,
                                                               b2, nullptr, hA_bf);

  // ---- layer 3: 256 -> 1x64, no ELU ----
  mfma_gemm_alpha_kernel<256><<<g64, 256, 0, stream>>>(hA_bf, Bt3, hX_bf, as3, ad3,
                                                       alp_s, alp_d, N_NODES, 64);
  softagg_kernel<64, false, false><<<N_NODES, 256, 0, stream>>>(row_ptr, csr_eid, src, ea,
                                                                alp_s, alp_d, proj + 24, hX_bf,
                                                                b3, hC, nullptr);

  // ---- classifier + softmax ----
  classifier_kernel<<<N_NODES * 64 / 256, 256, 0, stream>>>(hC, Wc, bc, out, N_NODES);
}